// Round 3
// baseline (23391.026 us; speedup 1.0000x reference)
//
#include <hip/hip_runtime.h>
#include <hip/hip_bf16.h>

#define DEV static __device__ __forceinline__

constexpr int Bc = 2048, Jc = 56, Dc = 256, Hc = 8, Dhc = 32, Lc = 4;
constexpr int Tc = 512;                 // threads per block
constexpr int OUT_TR = Bc * 330;        // 675840
constexpr int OUT_AW = OUT_TR + Bc;     // 677888

struct KP {
  const float *bp,*wrist,*betas;
  const float *pose_W1,*pose_b1,*pose_W2,*pose_b2;
  const float *joints,*mask_emb,*transl_emb,*in_g,*in_b;
  const float *gender_tab,*cond_W1,*cond_b1,*cond_W2,*cond_b2,*cond_g,*cond_b;
  const float *rel_map;
  const float *sa_Wqkv,*sa_bqkv,*sa_Wo,*sa_bo;
  const float *ca_Wkv,*ca_bkv,*ca_Wo,*ca_bo;
  const float *ff_W1,*ff_b1,*ff_W2,*ff_b2;
  const float *ln1_g,*ln1_b,*ln2_g,*ln2_b,*ln3_g,*ln3_b;
  const float *rot_W1,*rot_b1,*rot_W2,*rot_b2;
  const float *tr_W1,*tr_b1,*tr_W2,*tr_b2;
  const int *gender,*mask_ids;
  float* out;                           // fp32 output (evidence: out_npz 24MB ≈ fp32)
};

DEV float gelu_f(float x){
  // jax.nn.gelu approximate=True: 0.5x(1+tanh(z)) == x*sigmoid(2z)
  float z = 0.7978845608028654f * (x + 0.044715f * x * x * x);
  return x / (1.0f + __expf(-2.0f * z));
}
DEV float wred_sum(float v){
  #pragma unroll
  for (int m = 32; m; m >>= 1) v += __shfl_xor(v, m, 64);
  return v;
}
DEV float wred_max(float v){
  #pragma unroll
  for (int m = 32; m; m >>= 1) v = fmaxf(v, __shfl_xor(v, m, 64));
  return v;
}
DEV float f4c(const float4& v, int kk){ return kk==0?v.x : kk==1?v.y : kk==2?v.z : v.w; }

// in-place row LayerNorm over 56 rows x 256 cols; wave w owns rows 7w..7w+6
DEV void ln_rows(float (*xsr)[Dc], const float* g, const float* bta, int lane, int wv){
  #pragma unroll
  for (int q = 0; q < 7; ++q){
    int r = wv * 7 + q;
    float v[4]; float s = 0.f, s2 = 0.f;
    #pragma unroll
    for (int u = 0; u < 4; ++u){ v[u] = xsr[r][lane + 64*u]; s += v[u]; s2 = fmaf(v[u], v[u], s2); }
    s = wred_sum(s); s2 = wred_sum(s2);
    float mean = s * (1.f/256.f);
    float var  = s2 * (1.f/256.f) - mean * mean;
    float rs = rsqrtf(var + 1e-5f);
    #pragma unroll
    for (int u = 0; u < 4; ++u){
      int n = lane + 64*u;
      xsr[r][n] = (v[u] - mean) * rs * g[n] + bta[n];
    }
  }
}

// acc[7][4] += xs(56x256) @ W(256 x ldw)[:, ncol0 + lane + 64j]
DEV void gemm_std4(const float (*xsrc)[Dc], const float* W, int ldw, int ncol0,
                   float acc[7][4], int lane, int wv){
  for (int k = 0; k < 256; k += 4){
    float4 xv[7];
    #pragma unroll
    for (int i = 0; i < 7; ++i) xv[i] = *(const float4*)&xsrc[wv + 8*i][k];
    #pragma unroll
    for (int kk = 0; kk < 4; ++kk){
      float w[4];
      #pragma unroll
      for (int j = 0; j < 4; ++j) w[j] = W[(k+kk)*ldw + ncol0 + lane + 64*j];
      #pragma unroll
      for (int i = 0; i < 7; ++i){
        float xk = f4c(xv[i], kk);
        #pragma unroll
        for (int j = 0; j < 4; ++j) acc[i][j] = fmaf(xk, w[j], acc[i][j]);
      }
    }
  }
}

__global__ __launch_bounds__(Tc)
void actor_kernel(KP p){
  __shared__ float xs[Jc][Dc];        // 57344 B  activation, resident whole net
  __shared__ float sc[Jc][Jc];        // 12544 B  scores / scratch(1024)
  __shared__ float hb[4][Jc][Dhc];    // 28672 B  q,k,v,o head tiles / ff blocks
  __shared__ float aw[Jc][Jc];        // 12544 B  attn_w accumulator (layer 3)
  __shared__ float condv[Dc];         // 1024
  __shared__ float vcs[Dc];           // 1024
  __shared__ float tmpb[Tc];          // 2048

  const int t = threadIdx.x;
  const int lane = t & 63, wv = t >> 6;
  const int b = blockIdx.x;
  const float scale = 0.17677669529663687f; // 1/sqrt(32)

  float (*qh)[Dhc] = hb[0];
  float (*kh)[Dhc] = hb[1];
  float (*vh)[Dhc] = hb[2];
  float (*oh)[Dhc] = hb[3];

  // ---------------- cond MLP + LN ----------------
  if (t < 29){
    float v;
    if (t < 10) v = p.wrist[b*10 + t];
    else if (t < 13) v = p.betas[b*3 + (t-10)];
    else { int g = p.gender[b]; v = p.gender_tab[g*16 + (t-13)]; }
    vcs[t] = v;
  }
  __syncthreads();
  {
    float a = p.cond_b1[t];
    for (int k = 0; k < 29; ++k) a = fmaf(vcs[k], p.cond_W1[k*512 + t], a);
    tmpb[t] = gelu_f(a);
  }
  __syncthreads();
  if (t < 256){
    float a = p.cond_b2[t];
    for (int k = 0; k < 512; ++k) a = fmaf(tmpb[k], p.cond_W2[k*256 + t], a);
    condv[t] = a;
  }
  __syncthreads();
  if (wv == 0){
    float v[4], s = 0.f, s2 = 0.f;
    #pragma unroll
    for (int u = 0; u < 4; ++u){ v[u] = condv[lane + 64*u]; s += v[u]; s2 = fmaf(v[u], v[u], s2); }
    s = wred_sum(s); s2 = wred_sum(s2);
    float mean = s * (1.f/256.f);
    float var  = s2 * (1.f/256.f) - mean*mean;
    float rs = rsqrtf(var + 1e-5f);
    #pragma unroll
    for (int u = 0; u < 4; ++u){ int n = lane + 64*u; condv[n] = (v[u]-mean)*rs*p.cond_g[n] + p.cond_b[n]; }
  }
  __syncthreads();

  // ---------------- embed ----------------
  for (int i2 = t; i2 < 330; i2 += Tc) tmpb[i2] = p.bp[b*330 + i2];
  if (t < 256) xs[55][t] = 0.f;
  __syncthreads();
  {
    int n = t & 255, mb = t >> 8;
    for (int m = mb; m < 55; m += 2){
      float a = p.pose_b1[n];
      #pragma unroll
      for (int k = 0; k < 6; ++k) a = fmaf(tmpb[m*6 + k], p.pose_W1[k*256 + n], a);
      xs[m][n] = gelu_f(a);
    }
  }
  __syncthreads();
  {
    float acc[7][4] = {};
    gemm_std4(xs, p.pose_W2, 256, 0, acc, lane, wv);
    __syncthreads();  // all reads of xs(h1) done
    #pragma unroll
    for (int i = 0; i < 7; ++i){
      int m = wv + 8*i;
      #pragma unroll
      for (int j = 0; j < 4; ++j){
        int n = lane + 64*j;
        float v = (m < 55) ? (acc[i][j] + p.pose_b2[n]) : p.transl_emb[n];
        int mk = p.mask_ids[b*56 + m];
        v = mk ? v : p.mask_emb[n];
        v += p.joints[m*256 + n];
        xs[m][n] = v;
      }
    }
    __syncthreads();
    ln_rows(xs, p.in_g, p.in_b, lane, wv);
    __syncthreads();
  }

  // ---------------- layers ----------------
  for (int l = 0; l < Lc; ++l){
    float po[7][4] = {};
    const float* Wqkv = p.sa_Wqkv + l * (256*768);
    const float* bqkv = p.sa_bqkv + l * 768;
    const float* Wo   = p.sa_Wo   + l * 65536;

    for (int h = 0; h < Hc; ++h){
      // A1: q/k/v head tiles (56x32 each)
      {
        int cg = t & 31, mg = t >> 5;
        float aq[4] = {}, ak[4] = {}, av[4] = {};
        int cq = h*32 + cg, ck = 256 + h*32 + cg, cv = 512 + h*32 + cg;
        for (int k = 0; k < 256; k += 4){
          float4 xv[4];
          #pragma unroll
          for (int i = 0; i < 4; ++i){ int m = mg + 16*i; if (m > 55) m = 0; xv[i] = *(const float4*)&xs[m][k]; }
          #pragma unroll
          for (int kk = 0; kk < 4; ++kk){
            const float* wr = Wqkv + (k+kk)*768;
            float wq = wr[cq], wk = wr[ck], wvv = wr[cv];
            #pragma unroll
            for (int i = 0; i < 4; ++i){
              float xk = f4c(xv[i], kk);
              aq[i] = fmaf(xk, wq,  aq[i]);
              ak[i] = fmaf(xk, wk,  ak[i]);
              av[i] = fmaf(xk, wvv, av[i]);
            }
          }
        }
        #pragma unroll
        for (int i = 0; i < 4; ++i){
          int m = mg + 16*i;
          if (m < 56){
            qh[m][cg] = aq[i] + bqkv[cq];
            kh[m][cg] = ak[i] + bqkv[ck];
            vh[m][cg] = av[i] + bqkv[cv];
          }
        }
      }
      __syncthreads();
      // A2: scores = scale*q.k^T + rel_map
      for (int pg = t; pg < 3136; pg += Tc){
        int i = pg / 56, jj = pg - i * 56;
        float s = 0.f;
        #pragma unroll
        for (int k = 0; k < 32; k += 4){
          float4 qv = *(const float4*)&qh[i][k];
          float4 kv = *(const float4*)&kh[jj][k];
          s += qv.x*kv.x + qv.y*kv.y + qv.z*kv.z + qv.w*kv.w;
        }
        sc[i][jj] = s * scale + p.rel_map[pg];
      }
      __syncthreads();
      // A3: row softmax (+ attn_w accumulation in last layer)
      #pragma unroll
      for (int q = 0; q < 7; ++q){
        int r = wv*7 + q;
        float v = (lane < 56) ? sc[r][lane] : -3.0e38f;
        float mx = wred_max(v);
        float e = (lane < 56) ? __expf(v - mx) : 0.f;
        float s = wred_sum(e);
        float a = e / s;
        if (lane < 56){
          sc[r][lane] = a;
          if (l == 3) aw[r][lane] = (h == 0 ? 0.f : aw[r][lane]) + a * 0.125f;
        }
      }
      __syncthreads();
      // A4: oh = a @ vh
      {
        int d = t & 31, ig = t >> 5;
        float o4[4] = {};
        for (int j = 0; j < 56; ++j){
          float vvj = vh[j][d];
          #pragma unroll
          for (int i = 0; i < 4; ++i){
            int m = ig + 16*i; if (m > 55) m = 0;
            o4[i] = fmaf(sc[m][j], vvj, o4[i]);
          }
        }
        #pragma unroll
        for (int i = 0; i < 4; ++i){ int m = ig + 16*i; if (m < 56) oh[m][d] = o4[i]; }
      }
      __syncthreads();
      // A5: accumulate output projection po += oh @ Wo[h-rows]
      {
        const float* Woh = Wo + h * 32 * 256;
        for (int d = 0; d < 32; d += 4){
          float4 ov[7];
          #pragma unroll
          for (int i = 0; i < 7; ++i) ov[i] = *(const float4*)&oh[wv + 8*i][d];
          #pragma unroll
          for (int dd = 0; dd < 4; ++dd){
            float w[4];
            #pragma unroll
            for (int j = 0; j < 4; ++j) w[j] = Woh[(d+dd)*256 + lane + 64*j];
            #pragma unroll
            for (int i = 0; i < 7; ++i){
              float ok = f4c(ov[i], dd);
              #pragma unroll
              for (int j = 0; j < 4; ++j) po[i][j] = fmaf(ok, w[j], po[i][j]);
            }
          }
        }
      }
      __syncthreads();
    } // heads

    // B1: residual + bias + LN1
    #pragma unroll
    for (int i = 0; i < 7; ++i){ int m = wv + 8*i;
      #pragma unroll
      for (int j = 0; j < 4; ++j){ int n = lane + 64*j;
        xs[m][n] += po[i][j] + p.sa_bo[l*256 + n];
      }
    }
    __syncthreads();
    ln_rows(xs, p.ln1_g + l*256, p.ln1_b + l*256, lane, wv);
    __syncthreads();

    // B2: vc = cond @ ca_Wkv[:,256:512] + bkv[256:]   (kc & qc are dead: softmax over size-1 axis == 1)
    if (t < 256){
      float a = p.ca_bkv[l*512 + 256 + t];
      const float* W = p.ca_Wkv + l * 131072;
      for (int k = 0; k < 256; ++k) a = fmaf(condv[k], W[k*512 + 256 + t], a);
      vcs[t] = a;
    }
    __syncthreads();
    // B3: ocp = vc @ ca_Wo + ca_bo  (same row vector added to every token)
    if (t < 256){
      float a = p.ca_bo[l*256 + t];
      const float* W = p.ca_Wo + l * 65536;
      for (int k = 0; k < 256; ++k) a = fmaf(vcs[k], W[k*256 + t], a);
      tmpb[t] = a;
    }
    __syncthreads();
    #pragma unroll
    for (int i = 0; i < 7; ++i){ int m = wv + 8*i;
      #pragma unroll
      for (int j = 0; j < 4; ++j){ int n = lane + 64*j; xs[m][n] += tmpb[n]; }
    }
    __syncthreads();
    ln_rows(xs, p.ln2_g + l*256, p.ln2_b + l*256, lane, wv);
    __syncthreads();

    // B4: feed-forward, 16 blocks of 64 hidden cols, f1 block staged in hb[0..1]
    {
      float po2[7][4] = {};
      const float* W1 = p.ff_W1 + l * (256*1024);
      const float* b1 = p.ff_b1 + l * 1024;
      const float* W2 = p.ff_W2 + l * (1024*256);
      for (int kb = 0; kb < 16; ++kb){
        {
          int cg = t & 31, mg = t >> 5;
          float a8[2][4] = {};
          int col0 = kb*64 + cg, col1 = col0 + 32;
          for (int k = 0; k < 256; k += 4){
            float4 xv[4];
            #pragma unroll
            for (int i = 0; i < 4; ++i){ int m = mg + 16*i; if (m > 55) m = 0; xv[i] = *(const float4*)&xs[m][k]; }
            #pragma unroll
            for (int kk = 0; kk < 4; ++kk){
              float w0 = W1[(k+kk)*1024 + col0];
              float w1 = W1[(k+kk)*1024 + col1];
              #pragma unroll
              for (int i = 0; i < 4; ++i){
                float xk = f4c(xv[i], kk);
                a8[0][i] = fmaf(xk, w0, a8[0][i]);
                a8[1][i] = fmaf(xk, w1, a8[1][i]);
              }
            }
          }
          #pragma unroll
          for (int i = 0; i < 4; ++i){
            int m = mg + 16*i;
            if (m < 56){
              hb[0][m][cg] = gelu_f(a8[0][i] + b1[col0]);
              hb[1][m][cg] = gelu_f(a8[1][i] + b1[col1]);
            }
          }
        }
        __syncthreads();
        {
          for (int d = 0; d < 64; d += 4){
            float4 fv[7];
            #pragma unroll
            for (int i = 0; i < 7; ++i) fv[i] = *(const float4*)&hb[d>>5][wv + 8*i][d & 31];
            #pragma unroll
            for (int dd = 0; dd < 4; ++dd){
              float w[4];
              #pragma unroll
              for (int j = 0; j < 4; ++j) w[j] = W2[(kb*64 + d + dd)*256 + lane + 64*j];
              #pragma unroll
              for (int i = 0; i < 7; ++i){
                float fk = f4c(fv[i], dd);
                #pragma unroll
                for (int j = 0; j < 4; ++j) po2[i][j] = fmaf(fk, w[j], po2[i][j]);
              }
            }
          }
        }
        __syncthreads();
      }
      // B5: residual + bias + LN3
      #pragma unroll
      for (int i = 0; i < 7; ++i){ int m = wv + 8*i;
        #pragma unroll
        for (int j = 0; j < 4; ++j){ int n = lane + 64*j;
          xs[m][n] += po2[i][j] + p.ff_b2[l*256 + n];
        }
      }
      __syncthreads();
      ln_rows(xs, p.ln3_g + l*256, p.ln3_b + l*256, lane, wv);
      __syncthreads();
    }
  } // layers

  // ---------------- attn_w output (fp32) ----------------
  {
    const float* awf = &aw[0][0];
    for (int pg = t; pg < 3136; pg += Tc)
      p.out[OUT_AW + (size_t)b*3136 + pg] = awf[pg];
  }

  // ---------------- pose head ----------------
  {
    float pacc = 0.f;
    int mp = t / 6, op = t - mp * 6;  // valid for t<330
    for (int kb = 0; kb < 16; ++kb){
      {
        int cg = t & 31, mg = t >> 5;
        float a8[2][4] = {};
        int col0 = kb*64 + cg, col1 = col0 + 32;
        for (int k = 0; k < 256; k += 4){
          float4 xv[4];
          #pragma unroll
          for (int i = 0; i < 4; ++i){ int m = mg + 16*i; if (m > 55) m = 0; xv[i] = *(const float4*)&xs[m][k]; }
          #pragma unroll
          for (int kk = 0; kk < 4; ++kk){
            float w0 = p.rot_W1[(k+kk)*1024 + col0];
            float w1 = p.rot_W1[(k+kk)*1024 + col1];
            #pragma unroll
            for (int i = 0; i < 4; ++i){
              float xk = f4c(xv[i], kk);
              a8[0][i] = fmaf(xk, w0, a8[0][i]);
              a8[1][i] = fmaf(xk, w1, a8[1][i]);
            }
          }
        }
        #pragma unroll
        for (int i = 0; i < 4; ++i){
          int m = mg + 16*i;
          if (m < 56){
            hb[0][m][cg] = gelu_f(a8[0][i] + p.rot_b1[col0]);
            hb[1][m][cg] = gelu_f(a8[1][i] + p.rot_b1[col1]);
          }
        }
      }
      __syncthreads();
      if (t < 330){
        for (int d = 0; d < 64; ++d)
          pacc = fmaf(hb[d>>5][mp][d & 31], p.rot_W2[(kb*64 + d)*6 + op], pacc);
      }
      __syncthreads();
    }
    if (t < 330) p.out[(size_t)b*330 + t] = pacc + p.rot_b2[op];
  }

  // ---------------- transl head ----------------
  {
    float* scf = &sc[0][0]; // 1024-float scratch
    for (int c = t; c < 1024; c += Tc){
      float a = p.tr_b1[c];
      for (int k = 0; k < 256; ++k) a = fmaf(xs[55][k], p.tr_W1[k*1024 + c], a);
      scf[c] = gelu_f(a);
    }
    __syncthreads();
    float part = 0.f;
    for (int c = t; c < 1024; c += Tc) part = fmaf(scf[c], p.tr_W2[c], part);
    part = wred_sum(part);
    if (lane == 0) tmpb[wv] = part;
    __syncthreads();
    if (t == 0){
      float s = p.tr_b2[0];
      #pragma unroll
      for (int w2 = 0; w2 < 8; ++w2) s += tmpb[w2];
      p.out[OUT_TR + b] = s;
    }
  }
}

extern "C" void kernel_launch(void* const* d_in, const int* in_sizes, int n_in,
                              void* d_out, int out_size, void* d_ws, size_t ws_size,
                              hipStream_t stream){
  (void)in_sizes; (void)n_in; (void)out_size; (void)d_ws; (void)ws_size;

  // inputs are fp32 (in_npz 20.98 MB == fp32 raw size) -> read d_in directly
  auto F = [&](int i) -> const float* { return (const float*)d_in[i]; };

  KP p;
  p.bp = F(0); p.wrist = F(1); p.betas = F(2);
  p.pose_W1 = F(3); p.pose_b1 = F(4); p.pose_W2 = F(5); p.pose_b2 = F(6);
  p.joints = F(7); p.mask_emb = F(8); p.transl_emb = F(9);
  p.in_g = F(10); p.in_b = F(11);
  p.gender_tab = F(12);
  p.cond_W1 = F(13); p.cond_b1 = F(14); p.cond_W2 = F(15); p.cond_b2 = F(16);
  p.cond_g = F(17); p.cond_b = F(18);
  p.rel_map = F(19);
  p.sa_Wqkv = F(20); p.sa_bqkv = F(21); p.sa_Wo = F(22); p.sa_bo = F(23);
  p.ca_Wkv = F(26); p.ca_bkv = F(27); p.ca_Wo = F(28); p.ca_bo = F(29);
  p.ff_W1 = F(30); p.ff_b1 = F(31); p.ff_W2 = F(32); p.ff_b2 = F(33);
  p.ln1_g = F(34); p.ln1_b = F(35); p.ln2_g = F(36); p.ln2_b = F(37);
  p.ln3_g = F(38); p.ln3_b = F(39);
  p.rot_W1 = F(40); p.rot_b1 = F(41); p.rot_W2 = F(42); p.rot_b2 = F(43);
  p.tr_W1 = F(44); p.tr_b1 = F(45); p.tr_W2 = F(46); p.tr_b2 = F(47);
  p.gender = (const int*)d_in[48]; p.mask_ids = (const int*)d_in[49];
  p.out = (float*)d_out;

  hipLaunchKernelGGL(actor_kernel, dim3(Bc), dim3(Tc), 0, stream, p);
}

// Round 4
// 10248.141 us; speedup vs baseline: 2.2825x; 2.2825x over previous
//
#include <hip/hip_runtime.h>
#include <hip/hip_bf16.h>

#define DEV static __device__ __forceinline__

typedef __attribute__((ext_vector_type(8))) short short8;
typedef __attribute__((ext_vector_type(4))) short short4v;
typedef __attribute__((ext_vector_type(4))) float f32x4;
#define MFMA16(a,b,c) __builtin_amdgcn_mfma_f32_16x16x32_bf16(a,b,c,0,0,0)

constexpr int Bc = 2048, Tc = 512;
constexpr int OUT_TR = 675840;
constexpr int OUT_AW = 677888;

// ---- LDS map (bytes) ----
constexpr int XS_OFF   = 0;        // float xs[56][256]           57344
constexpr int CONDV    = 57344;    // float[256]                   1024
constexpr int VCS      = 58368;    // float[256]                   1024
constexpr int ARENA    = 59392;
constexpr int XB_OFF   = ARENA;            // ushort xb, stride 264 (29568 + spill)
constexpr int SLOTB    = ARENA + 29568;    // wbT96 [96][136] / h1c stride 264 / tmpf / wbTao[256][40]
constexpr int OH_OFF   = SLOTB + 20480;    // ushort oh[64][40]    5120
constexpr int WB2      = ARENA + 59136;    // wbt2: 2 x [256][40] ushort (40960)
constexpr int QB_OFF   = WB2;              // ushort qb[64][40]
constexpr int KB_OFF   = WB2 + 5120;       // ushort kb[64][40]
constexpr int VT_OFF   = WB2 + 10240;      // ushort vT[32][72]
constexpr int SC_OFF   = WB2 + 14848;      // float sc[56][56]
constexpr int SCB_OFF  = WB2 + 27392;      // ushort scb[64][72]
constexpr int SMEM_TOT = ARENA + 29568 + 29568 + 40960;  // 159488

struct KP {
  const float *bp,*wrist,*betas;
  const float *pose_W1,*pose_b1,*pose_W2,*pose_b2;
  const float *joints,*mask_emb,*transl_emb,*in_g,*in_b;
  const float *gender_tab,*cond_W1,*cond_b1,*cond_W2,*cond_b2,*cond_g,*cond_b;
  const float *rel_map;
  const float *sa_Wqkv,*sa_bqkv,*sa_Wo,*sa_bo;
  const float *ca_Wkv,*ca_bkv,*ca_Wo,*ca_bo;
  const float *ff_W1,*ff_b1,*ff_W2,*ff_b2;
  const float *ln1_g,*ln1_b,*ln2_g,*ln2_b,*ln3_g,*ln3_b;
  const float *rot_W1,*rot_b1,*rot_W2,*rot_b2;
  const float *tr_W1,*tr_b1,*tr_W2,*tr_b2;
  const int *gender,*mask_ids;
  float* out;
};

DEV unsigned short f2b(float x){
  union { __hip_bfloat16 h; unsigned short u; } c; c.h = __float2bfloat16(x); return c.u;
}
DEV float b2f(unsigned short u){
  union { __hip_bfloat16 h; unsigned short u; } c; c.u = u; return __bfloat162float(c.h);
}
DEV float gelu_f(float x){
  float z = 0.7978845608028654f * (x + 0.044715f * x * x * x);
  return x / (1.0f + __expf(-2.0f * z));
}
DEV float wred_sum(float v){
  #pragma unroll
  for (int m = 32; m; m >>= 1) v += __shfl_xor(v, m, 64);
  return v;
}
DEV float wred_max(float v){
  #pragma unroll
  for (int m = 32; m; m >>= 1) v = fmaxf(v, __shfl_xor(v, m, 64));
  return v;
}

// MFMA fragment load: lane l -> index0+(l&15) along M/N, k0+(l>>4)*8 along K
DEV short8 ldfrag(const unsigned short* base, int stride, int i0, int k0, int lane){
  return *(const short8*)(base + (i0 + (lane & 15)) * stride + k0 + ((lane >> 4) << 3));
}

// LayerNorm rows 7w..7w+6, optional bf16 mirror to xb
DEV void ln_rows(float* xs, unsigned short* xb, const float* g, const float* bta,
                 int lane, int wv, bool wxb){
  #pragma unroll
  for (int q = 0; q < 7; ++q){
    int r = wv * 7 + q;
    float v[4]; float s = 0.f, s2 = 0.f;
    #pragma unroll
    for (int u = 0; u < 4; ++u){ v[u] = xs[r*256 + lane + 64*u]; s += v[u]; s2 = fmaf(v[u], v[u], s2); }
    s = wred_sum(s); s2 = wred_sum(s2);
    float mean = s * (1.f/256.f);
    float var  = s2 * (1.f/256.f) - mean * mean;
    float rs = rsqrtf(var + 1e-5f);
    #pragma unroll
    for (int u = 0; u < 4; ++u){
      int n = lane + 64*u;
      float o = (v[u] - mean) * rs * g[n] + bta[n];
      xs[r*256 + n] = o;
      if (wxb) xb[r*264 + n] = f2b(o);
    }
  }
}

// stage one 32-k-slab of W[256 cols] into regs / wbT half ([col][k], stride 40)
DEV void stage_ld(const float* Wg, int ldw, int wrow0, int wcol0, int kofs, int t, float* r){
  #pragma unroll
  for (int i = 0; i < 4; ++i){
    int idx = t + i*512, col = idx & 255, k4 = idx >> 8;
    const float* src = Wg + (size_t)(wrow0 + kofs + k4*4) * ldw + wcol0 + col;
    #pragma unroll
    for (int rr = 0; rr < 4; ++rr) r[i*4+rr] = src[(size_t)rr * ldw];
  }
}
DEV void stage_wr(unsigned short* wbT, int t, const float* r){
  #pragma unroll
  for (int i = 0; i < 4; ++i){
    int idx = t + i*512, col = idx & 255, k4 = idx >> 8;
    short4v v;
    #pragma unroll
    for (int rr = 0; rr < 4; ++rr) v[rr] = (short)f2b(r[i*4+rr]);
    *(short4v*)(wbT + col*40 + k4*4) = v;
  }
}

// C[56(pad64) x 256] += A(bf16, stride 264) @ W[wrow0.. , wcol0..wcol0+255]; K=256, dbuf staging
DEV void gemm256(const unsigned short* A, const float* Wg, int ldw, int wrow0, int wcol0,
                 f32x4 acc[8], unsigned short* wbt2, int t, int lane, int wv){
  float rg[16];
  stage_ld(Wg, ldw, wrow0, wcol0, 0, t, rg);
  stage_wr(wbt2, t, rg);
  __syncthreads();
  int mt = wv & 3, cg = wv >> 2;
  for (int ks = 0; ks < 8; ++ks){
    if (ks < 7) stage_ld(Wg, ldw, wrow0, wcol0, (ks+1)*32, t, rg);
    unsigned short* wb = wbt2 + (ks & 1) * 10240;
    short8 a = ldfrag(A, 264, mt*16, ks*32, lane);
    #pragma unroll
    for (int ct = 0; ct < 8; ++ct){
      short8 bfr = ldfrag(wb, 40, cg*128 + ct*16, 0, lane);
      acc[ct] = MFMA16(a, bfr, acc[ct]);
    }
    if (ks < 7) stage_wr(wbt2 + ((ks+1)&1) * 10240, t, rg);
    __syncthreads();
  }
}

DEV void addC_to_xs(float* xs, const f32x4 acc[8], const float* bias, int lane, int wv){
  int mt = wv & 3, cg = wv >> 2;
  #pragma unroll
  for (int ct = 0; ct < 8; ++ct){
    int col = cg*128 + ct*16 + (lane & 15);
    #pragma unroll
    for (int j = 0; j < 4; ++j){
      int row = mt*16 + (lane >> 4)*4 + j;
      if (row < 56) xs[row*256 + col] += acc[ct][j] + bias[col];
    }
  }
}

__global__ __launch_bounds__(Tc)
void actor_kernel(KP p){
  __shared__ __align__(16) char smem[SMEM_TOT];
  float* xs      = (float*)(smem + XS_OFF);
  float* condv   = (float*)(smem + CONDV);
  float* vcs     = (float*)(smem + VCS);
  unsigned short* xb    = (unsigned short*)(smem + XB_OFF);
  unsigned short* wbT96 = (unsigned short*)(smem + SLOTB);
  unsigned short* wbTao = (unsigned short*)(smem + SLOTB);
  unsigned short* oh    = (unsigned short*)(smem + OH_OFF);
  unsigned short* h1c   = (unsigned short*)(smem + SLOTB);
  float* tmpf           = (float*)(smem + SLOTB);
  unsigned short* wbt2  = (unsigned short*)(smem + WB2);
  unsigned short* qb    = (unsigned short*)(smem + QB_OFF);
  unsigned short* kbuf  = (unsigned short*)(smem + KB_OFF);
  unsigned short* vT    = (unsigned short*)(smem + VT_OFF);
  float* scf            = (float*)(smem + SC_OFF);
  unsigned short* scb   = (unsigned short*)(smem + SCB_OFF);

  const int t = threadIdx.x;
  const int lane = t & 63, wv = t >> 6;
  const int mt = wv & 3, cg = wv >> 2;
  const int b = blockIdx.x;
  const float scale = 0.17677669529663687f; // 1/sqrt(32)
  const f32x4 fz = {0.f, 0.f, 0.f, 0.f};
  float awr[7] = {0.f,0.f,0.f,0.f,0.f,0.f,0.f};

  // ---------------- cond MLP + LN ----------------
  if (t < 29){
    float v;
    if (t < 10) v = p.wrist[b*10 + t];
    else if (t < 13) v = p.betas[b*3 + (t-10)];
    else { int g = p.gender[b]; v = p.gender_tab[g*16 + (t-13)]; }
    vcs[t] = v;
  }
  __syncthreads();
  {
    float a = p.cond_b1[t];
    for (int k = 0; k < 29; ++k) a = fmaf(vcs[k], p.cond_W1[k*512 + t], a);
    tmpf[t] = gelu_f(a);
  }
  __syncthreads();
  if (t < 256){
    float a = p.cond_b2[t];
    for (int k = 0; k < 512; ++k) a = fmaf(tmpf[k], p.cond_W2[k*256 + t], a);
    condv[t] = a;
  }
  __syncthreads();
  if (wv == 0){
    float v[4], s = 0.f, s2 = 0.f;
    #pragma unroll
    for (int u = 0; u < 4; ++u){ v[u] = condv[lane + 64*u]; s += v[u]; s2 = fmaf(v[u], v[u], s2); }
    s = wred_sum(s); s2 = wred_sum(s2);
    float mean = s * (1.f/256.f);
    float var  = s2 * (1.f/256.f) - mean*mean;
    float rs = rsqrtf(var + 1e-5f);
    #pragma unroll
    for (int u = 0; u < 4; ++u){ int n = lane + 64*u; condv[n] = (v[u]-mean)*rs*p.cond_g[n] + p.cond_b[n]; }
  }
  __syncthreads();

  // ---------------- embed ----------------
  for (int i2 = t; i2 < 330; i2 += Tc) tmpf[i2] = p.bp[b*330 + i2];
  __syncthreads();
  {
    int n = t & 255, mb = t >> 8;
    for (int m = mb; m < 55; m += 2){
      float a = p.pose_b1[n];
      #pragma unroll
      for (int k = 0; k < 6; ++k) a = fmaf(tmpf[m*6 + k], p.pose_W1[k*256 + n], a);
      xb[m*264 + n] = f2b(gelu_f(a));
    }
    if (t < 256) xb[55*264 + t] = 0;
  }
  __syncthreads();
  {
    f32x4 acc[8];
    #pragma unroll
    for (int ct = 0; ct < 8; ++ct) acc[ct] = fz;
    gemm256(xb, p.pose_W2, 256, 0, 0, acc, wbt2, t, lane, wv);
    #pragma unroll
    for (int ct = 0; ct < 8; ++ct){
      int col = cg*128 + ct*16 + (lane & 15);
      #pragma unroll
      for (int j = 0; j < 4; ++j){
        int row = mt*16 + (lane >> 4)*4 + j;
        if (row < 56){
          float v = (row < 55) ? (acc[ct][j] + p.pose_b2[col]) : p.transl_emb[col];
          v = p.mask_ids[b*56 + row] ? v : p.mask_emb[col];
          v += p.joints[row*256 + col];
          xs[row*256 + col] = v;
        }
      }
    }
    __syncthreads();
    ln_rows(xs, xb, p.in_g, p.in_b, lane, wv, true);
    __syncthreads();
  }

  // ---------------- layers ----------------
  for (int l = 0; l < 4; ++l){
    // zero vT pad keys (K-dim safety for PV)
    if (t < 256) vT[(t >> 3)*72 + 56 + (t & 7)] = 0;

    f32x4 po[8];
    #pragma unroll
    for (int ct = 0; ct < 8; ++ct) po[ct] = fz;

    const float* Wqkv = p.sa_Wqkv + (size_t)l * 196608;
    const float* bqkv = p.sa_bqkv + l * 768;
    const float* Wo   = p.sa_Wo   + (size_t)l * 65536;
    const float* rel  = p.rel_map;

    for (int h = 0; h < 8; ++h){
      // ---- QKV GEMM (N=96/head), 2 K-blocks of 128 ----
      f32x4 aq[3] = {fz, fz, fz};
      for (int kb2 = 0; kb2 < 2; ++kb2){
        float rg[24];
        #pragma unroll
        for (int i = 0; i < 6; ++i){
          int idx = t + i*512, c96 = idx % 96, k4 = idx / 96;
          int gcol = (c96 >> 5)*256 + h*32 + (c96 & 31);
          const float* src = Wqkv + (size_t)(kb2*128 + k4*4) * 768 + gcol;
          #pragma unroll
          for (int rr = 0; rr < 4; ++rr) rg[i*4+rr] = src[(size_t)rr * 768];
        }
        #pragma unroll
        for (int i = 0; i < 6; ++i){
          int idx = t + i*512, c96 = idx % 96, k4 = idx / 96;
          short4v v;
          #pragma unroll
          for (int rr = 0; rr < 4; ++rr) v[rr] = (short)f2b(rg[i*4+rr]);
          *(short4v*)(wbT96 + c96*136 + k4*4) = v;
        }
        __syncthreads();
        for (int ks = 0; ks < 4; ++ks){
          short8 a = ldfrag(xb, 264, mt*16, kb2*128 + ks*32, lane);
          #pragma unroll
          for (int ci = 0; ci < 3; ++ci){
            int ct = cg + 2*ci;
            short8 bf_ = ldfrag(wbT96, 136, ct*16, ks*32, lane);
            aq[ci] = MFMA16(a, bf_, aq[ci]);
          }
        }
        __syncthreads();
      }
      // C-write q/k/vT (bf16), scale folded into q
      #pragma unroll
      for (int ci = 0; ci < 3; ++ci){
        int ct = cg + 2*ci;
        int c96 = ct*16 + (lane & 15);
        int tens = c96 >> 5, d = c96 & 31;
        float bias = bqkv[tens*256 + h*32 + d];
        #pragma unroll
        for (int j = 0; j < 4; ++j){
          int row = mt*16 + (lane >> 4)*4 + j;
          if (row < 56){
            float v = aq[ci][j] + bias;
            if (tens == 0)      qb[row*40 + d] = f2b(v * scale);
            else if (tens == 1) kbuf[row*40 + d] = f2b(v);
            else                vT[d*72 + row] = f2b(v);
          }
        }
      }
      __syncthreads();
      // ---- scores: s = q @ k^T + rel ----
      {
        int c2 = wv >> 2;
        short8 a = ldfrag(qb, 40, mt*16, 0, lane);
        #pragma unroll
        for (int ci = 0; ci < 2; ++ci){
          int ct = c2 + 2*ci;
          short8 bf_ = ldfrag(kbuf, 40, ct*16, 0, lane);
          f32x4 d = MFMA16(a, bf_, fz);
          #pragma unroll
          for (int j = 0; j < 4; ++j){
            int q = mt*16 + (lane >> 4)*4 + j, key = ct*16 + (lane & 15);
            if (q < 56 && key < 56) scf[q*56 + key] = d[j] + rel[q*56 + key];
          }
        }
      }
      __syncthreads();
      // ---- softmax (fp32) -> scb bf16; attn_w regs on l==3 ----
      #pragma unroll
      for (int q = 0; q < 7; ++q){
        int r = wv*7 + q;
        float v = (lane < 56) ? scf[r*56 + lane] : -3.0e38f;
        float mx = wred_max(v);
        float e = (lane < 56) ? __expf(v - mx) : 0.f;
        float s = wred_sum(e);
        float a = e / s;
        scb[r*72 + lane] = (lane < 56) ? f2b(a) : (unsigned short)0;
        if (l == 3) awr[q] += a * 0.125f;
      }
      __syncthreads();
      // ---- PV: o = P @ v  (A=scb, B=vT) ----
      {
        int ct = wv >> 2;
        f32x4 o = fz;
        for (int ks = 0; ks < 2; ++ks){
          short8 a = ldfrag(scb, 72, mt*16, ks*32, lane);
          short8 bf_ = ldfrag(vT, 72, ct*16, ks*32, lane);
          o = MFMA16(a, bf_, o);
        }
        #pragma unroll
        for (int j = 0; j < 4; ++j){
          int row = mt*16 + (lane >> 4)*4 + j;
          if (row < 56) oh[row*40 + ct*16 + (lane & 15)] = f2b(o[j]);
        }
      }
      __syncthreads();
      // ---- AO: po += o_h @ Wo[h-rows]  (K=32) ----
      {
        float rg[16];
        stage_ld(Wo, 256, h*32, 0, 0, t, rg);
        stage_wr(wbTao, t, rg);
      }
      __syncthreads();
      {
        short8 a = ldfrag(oh, 40, mt*16, 0, lane);
        #pragma unroll
        for (int ct = 0; ct < 8; ++ct){
          short8 bf_ = ldfrag(wbTao, 40, cg*128 + ct*16, 0, lane);
          po[ct] = MFMA16(a, bf_, po[ct]);
        }
      }
      __syncthreads();
    } // heads

    // B1: residual + bias + LN1
    addC_to_xs(xs, po, p.sa_bo + l*256, lane, wv);
    __syncthreads();
    ln_rows(xs, xb, p.ln1_g + l*256, p.ln1_b + l*256, lane, wv, false);
    __syncthreads();

    // B2/B3: collapsed cross-attention (softmax over 1 key == 1)
    if (t < 256){
      float a = p.ca_bkv[l*512 + 256 + t];
      const float* W = p.ca_Wkv + (size_t)l * 131072;
      for (int k = 0; k < 256; ++k) a = fmaf(condv[k], W[k*512 + 256 + t], a);
      vcs[t] = a;
    }
    __syncthreads();
    if (t < 256){
      float a = p.ca_bo[l*256 + t];
      const float* W = p.ca_Wo + (size_t)l * 65536;
      for (int k = 0; k < 256; ++k) a = fmaf(vcs[k], W[k*256 + t], a);
      tmpf[t] = a;
    }
    __syncthreads();
    #pragma unroll
    for (int q = 0; q < 7; ++q){
      int r = wv*7 + q;
      #pragma unroll
      for (int u = 0; u < 4; ++u){ int n = lane + 64*u; xs[r*256 + n] += tmpf[n]; }
    }
    __syncthreads();
    ln_rows(xs, xb, p.ln2_g + l*256, p.ln2_b + l*256, lane, wv, true);
    __syncthreads();

    // FF: 4 chunks of 256 hidden cols
    {
      f32x4 po2[8];
      #pragma unroll
      for (int ct = 0; ct < 8; ++ct) po2[ct] = fz;
      const float* W1 = p.ff_W1 + (size_t)l * 262144;
      const float* b1 = p.ff_b1 + l * 1024;
      const float* W2 = p.ff_W2 + (size_t)l * 262144;
      for (int c = 0; c < 4; ++c){
        f32x4 fa[8];
        #pragma unroll
        for (int ct = 0; ct < 8; ++ct) fa[ct] = fz;
        gemm256(xb, W1, 1024, 0, c*256, fa, wbt2, t, lane, wv);
        #pragma unroll
        for (int ct = 0; ct < 8; ++ct){
          int col = cg*128 + ct*16 + (lane & 15);
          #pragma unroll
          for (int j = 0; j < 4; ++j){
            int row = mt*16 + (lane >> 4)*4 + j;
            if (row < 56) h1c[row*264 + col] = f2b(gelu_f(fa[ct][j] + b1[c*256 + col]));
          }
        }
        gemm256(h1c, W2, 256, c*256, 0, po2, wbt2, t, lane, wv);
      }
      addC_to_xs(xs, po2, p.ff_b2 + l*256, lane, wv);
      __syncthreads();
      ln_rows(xs, xb, p.ln3_g + l*256, p.ln3_b + l*256, lane, wv, true);
      __syncthreads();
    }
  } // layers

  // ---------------- attn_w output ----------------
  if (lane < 56){
    #pragma unroll
    for (int q = 0; q < 7; ++q)
      p.out[OUT_AW + (size_t)b*3136 + (wv*7 + q)*56 + lane] = awr[q];
  }

  // ---------------- pose head ----------------
  {
    float pacc = 0.f;
    int mp = t / 6, op = t - mp*6;
    for (int c = 0; c < 4; ++c){
      f32x4 pa[8];
      #pragma unroll
      for (int ct = 0; ct < 8; ++ct) pa[ct] = fz;
      gemm256(xb, p.rot_W1, 1024, 0, c*256, pa, wbt2, t, lane, wv);
      #pragma unroll
      for (int ct = 0; ct < 8; ++ct){
        int col = cg*128 + ct*16 + (lane & 15);
        #pragma unroll
        for (int j = 0; j < 4; ++j){
          int row = mt*16 + (lane >> 4)*4 + j;
          if (row < 56) h1c[row*264 + col] = f2b(gelu_f(pa[ct][j] + p.rot_b1[c*256 + col]));
        }
      }
      __syncthreads();
      if (t < 330){
        for (int d = 0; d < 256; ++d)
          pacc = fmaf(b2f(h1c[mp*264 + d]), p.rot_W2[(size_t)(c*256 + d)*6 + op], pacc);
      }
      __syncthreads();
    }
    if (t < 330) p.out[(size_t)b*330 + t] = pacc + p.rot_b2[op];
  }

  // ---------------- transl head ----------------
  {
    float* trf = (float*)(smem + WB2);  // 1024-float scratch (wbt2 dead)
    for (int c = t; c < 1024; c += Tc){
      float a = p.tr_b1[c];
      for (int k = 0; k < 256; ++k) a = fmaf(xs[55*256 + k], p.tr_W1[k*1024 + c], a);
      trf[c] = gelu_f(a);
    }
    __syncthreads();
    float part = 0.f;
    for (int c = t; c < 1024; c += Tc) part = fmaf(trf[c], p.tr_W2[c], part);
    part = wred_sum(part);
    if (lane == 0) vcs[wv] = part;
    __syncthreads();
    if (t == 0){
      float s = p.tr_b2[0];
      #pragma unroll
      for (int w2 = 0; w2 < 8; ++w2) s += vcs[w2];
      p.out[OUT_TR + b] = s;
    }
  }
}

extern "C" void kernel_launch(void* const* d_in, const int* in_sizes, int n_in,
                              void* d_out, int out_size, void* d_ws, size_t ws_size,
                              hipStream_t stream){
  (void)in_sizes; (void)n_in; (void)out_size; (void)d_ws; (void)ws_size;
  auto F = [&](int i) -> const float* { return (const float*)d_in[i]; };

  KP p;
  p.bp = F(0); p.wrist = F(1); p.betas = F(2);
  p.pose_W1 = F(3); p.pose_b1 = F(4); p.pose_W2 = F(5); p.pose_b2 = F(6);
  p.joints = F(7); p.mask_emb = F(8); p.transl_emb = F(9);
  p.in_g = F(10); p.in_b = F(11);
  p.gender_tab = F(12);
  p.cond_W1 = F(13); p.cond_b1 = F(14); p.cond_W2 = F(15); p.cond_b2 = F(16);
  p.cond_g = F(17); p.cond_b = F(18);
  p.rel_map = F(19);
  p.sa_Wqkv = F(20); p.sa_bqkv = F(21); p.sa_Wo = F(22); p.sa_bo = F(23);
  p.ca_Wkv = F(26); p.ca_bkv = F(27); p.ca_Wo = F(28); p.ca_bo = F(29);
  p.ff_W1 = F(30); p.ff_b1 = F(31); p.ff_W2 = F(32); p.ff_b2 = F(33);
  p.ln1_g = F(34); p.ln1_b = F(35); p.ln2_g = F(36); p.ln2_b = F(37);
  p.ln3_g = F(38); p.ln3_b = F(39);
  p.rot_W1 = F(40); p.rot_b1 = F(41); p.rot_W2 = F(42); p.rot_b2 = F(43);
  p.tr_W1 = F(44); p.tr_b1 = F(45); p.tr_W2 = F(46); p.tr_b2 = F(47);
  p.gender = (const int*)d_in[48]; p.mask_ids = (const int*)d_in[49];
  p.out = (float*)d_out;

  hipLaunchKernelGGL(actor_kernel, dim3(Bc), dim3(Tc), 0, stream, p);
}

// Round 5
// 8932.534 us; speedup vs baseline: 2.6186x; 1.1473x over previous
//
#include <hip/hip_runtime.h>
#include <hip/hip_bf16.h>

#define DEV static __device__ __forceinline__

typedef __attribute__((ext_vector_type(8))) short short8;
typedef __attribute__((ext_vector_type(4))) float f32x4;
#define MFMA16(a,b,c) __builtin_amdgcn_mfma_f32_16x16x32_bf16(a,b,c,0,0,0)

constexpr int Bc = 2048, Tc = 512;
constexpr int OUT_TR = 675840;
constexpr int OUT_AW = 677888;
constexpr int XSTR = 260;              // xs row stride (floats), 2-way banks

// ---- d_ws bf16 layout (ushort element offsets) ----
constexpr unsigned WQKV  = 0;          // l4 x h8 x ks8 x ct6 x 512   (q-scale folded)
constexpr unsigned WO    = 786432;     // l4 x h8 x ct16 x 512
constexpr unsigned WF1   = 1048576;    // l4 x ch4 x ks8 x ct16 x 512
constexpr unsigned WF2   = 2097152;    // l4 x ch4(k) x ks8 x ct16 x 512
constexpr unsigned WROT  = 3145728;    // ch4 x ks8 x ct16 x 512
constexpr unsigned WP2   = 3407872;    // ks8 x ct16 x 512
constexpr unsigned WCAV  = 3473408;    // l4 x k256 x col256 (row-major)
constexpr unsigned WCAO  = 3735552;    // l4 x k256 x col256
constexpr unsigned WCND2 = 3997696;    // k512 x col256
constexpr unsigned WTR1  = 4128768;    // k256 x col1024
constexpr unsigned WTOT  = 4390912;    // 8.78 MB

// ---- LDS map (bytes) ----
constexpr int XS    = 0;               // float [56][260]      58240
constexpr int CONDV = 58240;           // float[256]
constexpr int VCS   = 59264;           // float[256]
constexpr int WSTO  = 60288;           // staging arena 49152 (QKV 48K / dbuf 2x8K / AO 16K)
constexpr int QB    = 109440;          // ushort [64][40]  (also bp float stage)
constexpr int KB    = 114560;          // ushort [64][40]
constexpr int VT    = 119680;          // ushort [32][72]
constexpr int OH    = 124288;          // ushort [64][40]
constexpr int R3    = 129408;          // 33792: h1c ushort[64][264] / scf f32[56][60]+scb / tmpf / trf
constexpr int SCBO  = R3 + 13440;      // ushort [64][72]
constexpr int SMEM_TOT = R3 + 33792;   // 163200 <= 163840

struct PP {
  const float *sa_Wqkv,*sa_Wo,*ff_W1,*ff_W2,*rot_W1,*pose_W2,*ca_Wkv,*ca_Wo,*cond_W2,*tr_W1;
  unsigned short* wb;
};
struct KP {
  const float *bp,*wrist,*betas;
  const float *pose_W1,*pose_b1,*pose_b2;
  const float *joints,*mask_emb,*transl_emb,*in_g,*in_b;
  const float *gender_tab,*cond_W1,*cond_b1,*cond_b2,*cond_g,*cond_b;
  const float *rel_map;
  const float *sa_bqkv,*sa_bo;
  const float *ca_bkv,*ca_bo;
  const float *ff_b1,*ff_b2;
  const float *ln1_g,*ln1_b,*ln2_g,*ln2_b,*ln3_g,*ln3_b;
  const float *rot_b1,*rot_W2,*rot_b2;
  const float *tr_b1,*tr_W2,*tr_b2;
  const int *gender,*mask_ids;
  const unsigned short* wb;
  float* out;
};

DEV unsigned short f2b(float x){
  union { __hip_bfloat16 h; unsigned short u; } c; c.h = __float2bfloat16(x); return c.u;
}
DEV float b2f(unsigned short u){
  union { __hip_bfloat16 h; unsigned short u; } c; c.u = u; return __bfloat162float(c.h);
}
DEV float gelu_f(float x){
  float z = 0.7978845608028654f * (x + 0.044715f * x * x * x);
  return x / (1.0f + __expf(-2.0f * z));
}
DEV float wred_sum(float v){
  #pragma unroll
  for (int m = 32; m; m >>= 1) v += __shfl_xor(v, m, 64);
  return v;
}
DEV float wred_max(float v){
  #pragma unroll
  for (int m = 32; m; m >>= 1) v = fmaxf(v, __shfl_xor(v, m, 64));
  return v;
}

// ================= prep: fp32 weights -> bf16 fragment-linear in d_ws =================
__global__ __launch_bounds__(256)
void prep_kernel(PP a){
  unsigned i = blockIdx.x*256u + threadIdx.x;
  if (i >= WTOT) return;
  float v;
  if (i < WO){                                   // WQKV
    unsigned l=i/196608u, r=i%196608u, h=r/24576u, r2=r%24576u;
    unsigned ks=r2/3072u, r3=r2%3072u, ct=r3/512u, r4=r3%512u;
    unsigned lane=r4>>3, e=r4&7u;
    unsigned c96=ct*16u+(lane&15u), k=ks*32u+((lane>>4)<<3)+e;
    unsigned part=c96>>5, d=c96&31u;
    v = a.sa_Wqkv[l*196608u + k*768u + part*256u + h*32u + d];
    if (part==0u) v *= 0.17677669529663687f;
  } else if (i < WF1){                           // WO
    unsigned j=i-WO, l=j/65536u, r=j%65536u, h=r/8192u, r2=r%8192u;
    unsigned ct=r2/512u, r4=r2%512u, lane=r4>>3, e=r4&7u;
    unsigned col=ct*16u+(lane&15u), k=((lane>>4)<<3)+e;
    v = a.sa_Wo[l*65536u + (h*32u+k)*256u + col];
  } else if (i < WF2){                           // WF1
    unsigned j=i-WF1, l=j/262144u, r=j%262144u, ch=r/65536u, r2=r%65536u;
    unsigned ks=r2/8192u, r3=r2%8192u, ct=r3/512u, r4=r3%512u, lane=r4>>3, e=r4&7u;
    unsigned col=ch*256u+ct*16u+(lane&15u), k=ks*32u+((lane>>4)<<3)+e;
    v = a.ff_W1[l*262144u + k*1024u + col];
  } else if (i < WROT){                          // WF2
    unsigned j=i-WF2, l=j/262144u, r=j%262144u, ch=r/65536u, r2=r%65536u;
    unsigned ks=r2/8192u, r3=r2%8192u, ct=r3/512u, r4=r3%512u, lane=r4>>3, e=r4&7u;
    unsigned col=ct*16u+(lane&15u), k=ch*256u+ks*32u+((lane>>4)<<3)+e;
    v = a.ff_W2[l*262144u + k*256u + col];
  } else if (i < WP2){                           // WROT
    unsigned j=i-WROT, ch=j/65536u, r2=j%65536u;
    unsigned ks=r2/8192u, r3=r2%8192u, ct=r3/512u, r4=r3%512u, lane=r4>>3, e=r4&7u;
    unsigned col=ch*256u+ct*16u+(lane&15u), k=ks*32u+((lane>>4)<<3)+e;
    v = a.rot_W1[k*1024u + col];
  } else if (i < WCAV){                          // WP2
    unsigned j=i-WP2, ks=j/8192u, r3=j%8192u;
    unsigned ct=r3/512u, r4=r3%512u, lane=r4>>3, e=r4&7u;
    unsigned col=ct*16u+(lane&15u), k=ks*32u+((lane>>4)<<3)+e;
    v = a.pose_W2[k*256u + col];
  } else if (i < WCAO){                          // WCAV
    unsigned j=i-WCAV, l=j/65536u, r=j%65536u, k=r>>8, col=r&255u;
    v = a.ca_Wkv[l*131072u + k*512u + 256u + col];
  } else if (i < WCND2){                         // WCAO
    unsigned j=i-WCAO, l=j/65536u, r=j%65536u, k=r>>8, col=r&255u;
    v = a.ca_Wo[l*65536u + k*256u + col];
  } else if (i < WTR1){                          // WCND2
    unsigned j=i-WCND2, k=j>>8, col=j&255u;
    v = a.cond_W2[k*256u + col];
  } else {                                       // WTR1
    unsigned j=i-WTR1, k=j/1024u, col=j%1024u;
    v = a.tr_W1[k*1024u + col];
  }
  a.wb[i] = f2b(v);
}

// ================= main kernel helpers =================
DEV void ln_rows(float* xs, const float* g, const float* bta, int lane, int wv){
  #pragma unroll
  for (int q = 0; q < 7; ++q){
    int r = wv*7 + q;
    float v[4]; float s = 0.f, s2 = 0.f;
    #pragma unroll
    for (int u = 0; u < 4; ++u){ v[u] = xs[r*XSTR + lane + 64*u]; s += v[u]; s2 = fmaf(v[u], v[u], s2); }
    s = wred_sum(s); s2 = wred_sum(s2);
    float mean = s * (1.f/256.f);
    float var  = s2 * (1.f/256.f) - mean*mean;
    float rs = rsqrtf(var + 1e-5f);
    #pragma unroll
    for (int u = 0; u < 4; ++u){
      int n = lane + 64*u;
      xs[r*XSTR + n] = (v[u]-mean)*rs*g[n] + bta[n];
    }
  }
}

// build per-wave A fragments (x rows mt*16..mt*16+15, K=256) from fp32 xs
DEV void build_afr(const float* xs, short8 afr[8], int lane, int mt){
  int row = mt*16 + (lane & 15);
  const float* rp = xs + row*XSTR + ((lane >> 4) << 3);
  #pragma unroll
  for (int ks = 0; ks < 8; ++ks){
    float4 a = *(const float4*)(rp + ks*32);
    float4 b = *(const float4*)(rp + ks*32 + 4);
    short8 v;
    v[0]=(short)f2b(a.x); v[1]=(short)f2b(a.y); v[2]=(short)f2b(a.z); v[3]=(short)f2b(a.w);
    v[4]=(short)f2b(b.x); v[5]=(short)f2b(b.y); v[6]=(short)f2b(b.z); v[7]=(short)f2b(b.w);
    afr[ks] = v;
  }
}

// N=256, K=256 GEMM, B from frag-linear global (8 slabs x 8192 elems), dbuf pipeline
template<bool AREG>
DEV void gemm_pipe(const unsigned short* Wg, unsigned short* wst,
                   const short8* afr, const unsigned short* Albs,
                   f32x4* acc, int t, int lane, int mt, int cg){
  short8 r0 = *(const short8*)(Wg + t*8);
  short8 r1 = *(const short8*)(Wg + (t+512)*8);
  *(short8*)(wst + t*8) = r0;
  *(short8*)(wst + (t+512)*8) = r1;
  __syncthreads();
  #pragma unroll
  for (int ks = 0; ks < 8; ++ks){
    if (ks < 7){
      r0 = *(const short8*)(Wg + (ks+1)*8192 + t*8);
      r1 = *(const short8*)(Wg + (ks+1)*8192 + (t+512)*8);
    }
    const unsigned short* wbuf = wst + (ks&1)*8192;
    short8 a;
    if (AREG) a = afr[ks];
    else      a = *(const short8*)(Albs + (mt*16 + (lane&15))*264 + ks*32 + ((lane>>4)<<3));
    #pragma unroll
    for (int c = 0; c < 8; ++c){
      short8 bf_ = *(const short8*)(wbuf + (cg*8 + c)*512 + lane*8);
      acc[c] = MFMA16(a, bf_, acc[c]);
    }
    if (ks < 7){
      *(short8*)(wst + ((ks+1)&1)*8192 + t*8) = r0;
      *(short8*)(wst + ((ks+1)&1)*8192 + (t+512)*8) = r1;
    }
    __syncthreads();
  }
}

DEV void addC_to_xs(float* xs, const f32x4* acc, const float* bias, int lane, int wv){
  int mt = wv & 3, cg = wv >> 2;
  #pragma unroll
  for (int c = 0; c < 8; ++c){
    int col = cg*128 + c*16 + (lane & 15);
    #pragma unroll
    for (int j = 0; j < 4; ++j){
      int row = mt*16 + (lane >> 4)*4 + j;
      if (row < 56) xs[row*XSTR + col] += acc[c][j] + bias[col];
    }
  }
}

__global__ __launch_bounds__(Tc)
void actor_kernel(KP p){
  __shared__ __align__(16) char smem[SMEM_TOT];
  float* xs    = (float*)(smem + XS);
  float* condv = (float*)(smem + CONDV);
  float* vcs   = (float*)(smem + VCS);
  unsigned short* wst = (unsigned short*)(smem + WSTO);
  unsigned short* qb  = (unsigned short*)(smem + QB);
  unsigned short* kb  = (unsigned short*)(smem + KB);
  unsigned short* vT  = (unsigned short*)(smem + VT);
  unsigned short* oh  = (unsigned short*)(smem + OH);
  unsigned short* h1c = (unsigned short*)(smem + R3);
  float* scf   = (float*)(smem + R3);
  unsigned short* scb = (unsigned short*)(smem + SCBO);
  float* tmpf  = (float*)(smem + R3);
  float* bpf   = (float*)(smem + QB);

  const int t = threadIdx.x;
  const int lane = t & 63, wv = t >> 6;
  const int mt = wv & 3, cg = wv >> 2;
  const int b = blockIdx.x;
  const f32x4 fz = {0.f, 0.f, 0.f, 0.f};
  const unsigned short* wsQ   = p.wb + WQKV;
  const unsigned short* wsO   = p.wb + WO;
  const unsigned short* wsF1  = p.wb + WF1;
  const unsigned short* wsF2  = p.wb + WF2;
  const unsigned short* wsROT = p.wb + WROT;
  const unsigned short* wsP2  = p.wb + WP2;
  const unsigned short* wsCAV = p.wb + WCAV;
  const unsigned short* wsCAO = p.wb + WCAO;
  const unsigned short* wsC2  = p.wb + WCND2;
  const unsigned short* wsTR  = p.wb + WTR1;
  float awr[7] = {0.f,0.f,0.f,0.f,0.f,0.f,0.f};
  short8 afr[8];

  // ---------------- cond MLP + LN ----------------
  if (t < 29){
    float v;
    if (t < 10) v = p.wrist[b*10 + t];
    else if (t < 13) v = p.betas[b*3 + (t-10)];
    else { int g = p.gender[b]; v = p.gender_tab[g*16 + (t-13)]; }
    vcs[t] = v;
  }
  __syncthreads();
  {
    float a = p.cond_b1[t];
    for (int k = 0; k < 29; ++k) a = fmaf(vcs[k], p.cond_W1[k*512 + t], a);
    tmpf[t] = gelu_f(a);
  }
  __syncthreads();
  if (t < 256){
    float a = p.cond_b2[t];
    for (int k = 0; k < 512; ++k) a = fmaf(tmpf[k], b2f(wsC2[k*256 + t]), a);
    condv[t] = a;
  }
  __syncthreads();
  if (wv == 0){
    float v[4], s = 0.f, s2 = 0.f;
    #pragma unroll
    for (int u = 0; u < 4; ++u){ v[u] = condv[lane + 64*u]; s += v[u]; s2 = fmaf(v[u], v[u], s2); }
    s = wred_sum(s); s2 = wred_sum(s2);
    float mean = s * (1.f/256.f);
    float var  = s2 * (1.f/256.f) - mean*mean;
    float rs = rsqrtf(var + 1e-5f);
    #pragma unroll
    for (int u = 0; u < 4; ++u){ int n = lane + 64*u; condv[n] = (v[u]-mean)*rs*p.cond_g[n] + p.cond_b[n]; }
  }
  __syncthreads();

  // ---------------- embed ----------------
  for (int i2 = t; i2 < 330; i2 += Tc) bpf[i2] = p.bp[b*330 + i2];
  __syncthreads();
  {
    int n = t & 255, mb = t >> 8;
    for (int m = mb; m < 55; m += 2){
      float a = p.pose_b1[n];
      #pragma unroll
      for (int k = 0; k < 6; ++k) a = fmaf(bpf[m*6 + k], p.pose_W1[k*256 + n], a);
      h1c[m*264 + n] = f2b(gelu_f(a));
    }
    if (t < 256) h1c[55*264 + t] = 0;
  }
  __syncthreads();
  {
    f32x4 acc[8];
    #pragma unroll
    for (int c = 0; c < 8; ++c) acc[c] = fz;
    gemm_pipe<false>(wsP2, wst, nullptr, h1c, acc, t, lane, mt, cg);
    #pragma unroll
    for (int c = 0; c < 8; ++c){
      int col = cg*128 + c*16 + (lane & 15);
      #pragma unroll
      for (int j = 0; j < 4; ++j){
        int row = mt*16 + (lane >> 4)*4 + j;
        if (row < 56){
          float v = (row < 55) ? (acc[c][j] + p.pose_b2[col]) : p.transl_emb[col];
          v = p.mask_ids[b*56 + row] ? v : p.mask_emb[col];
          v += p.joints[row*256 + col];
          xs[row*XSTR + col] = v;
        }
      }
    }
    __syncthreads();
    ln_rows(xs, p.in_g, p.in_b, lane, wv);
    __syncthreads();
    build_afr(xs, afr, lane, mt);
  }

  // ---------------- layers ----------------
  for (int l = 0; l < 4; ++l){
    if (t < 256) vT[(t >> 3)*72 + 56 + (t & 7)] = 0;  // K-pad for PV

    f32x4 po[8];
    #pragma unroll
    for (int c = 0; c < 8; ++c) po[c] = fz;
    const float* bqkv = p.sa_bqkv + l*768;

    for (int h = 0; h < 8; ++h){
      // ---- stage whole-head QKV W (48KB frag-linear) ----
      {
        const unsigned short* gW = wsQ + ((size_t)(l*8 + h)) * 24576;
        short8 s[6];
        #pragma unroll
        for (int r = 0; r < 6; ++r) s[r] = *(const short8*)(gW + (t + r*512)*8);
        #pragma unroll
        for (int r = 0; r < 6; ++r) *(short8*)(wst + (t + r*512)*8) = s[r];
      }
      __syncthreads();
      // ---- QKV MFMA ----
      f32x4 aq[3] = {fz, fz, fz};
      #pragma unroll
      for (int ks = 0; ks < 8; ++ks){
        #pragma unroll
        for (int ci = 0; ci < 3; ++ci){
          int ct = cg + 2*ci;
          short8 bf_ = *(const short8*)(wst + (ks*6 + ct)*512 + lane*8);
          aq[ci] = MFMA16(afr[ks], bf_, aq[ci]);
        }
      }
      // ---- C-write q/k/vT ----
      #pragma unroll
      for (int ci = 0; ci < 3; ++ci){
        int ct = cg + 2*ci;
        int c96 = ct*16 + (lane & 15);
        int part = c96 >> 5, d = c96 & 31;
        float bias = bqkv[part*256 + h*32 + d];
        if (part == 0) bias *= 0.17677669529663687f;
        #pragma unroll
        for (int j = 0; j < 4; ++j){
          int row = mt*16 + (lane >> 4)*4 + j;
          if (row < 56){
            float v = aq[ci][j] + bias;
            if (part == 0)      qb[row*40 + d] = f2b(v);
            else if (part == 1) kb[row*40 + d] = f2b(v);
            else                vT[d*72 + row] = f2b(v);
          }
        }
      }
      __syncthreads();
      // ---- issue AO weight loads (land during scores/softmax/PV) ----
      const unsigned short* gAO = wsO + ((size_t)(l*8 + h)) * 8192;
      short8 a0 = *(const short8*)(gAO + t*8);
      short8 a1 = *(const short8*)(gAO + (t+512)*8);
      // ---- scores = q@k^T + rel ----
      {
        int c2 = wv >> 2;
        short8 a = *(const short8*)(qb + (mt*16 + (lane&15))*40 + ((lane>>4)<<3));
        #pragma unroll
        for (int ci = 0; ci < 2; ++ci){
          int ct = c2 + 2*ci;
          short8 bf_ = *(const short8*)(kb + (ct*16 + (lane&15))*40 + ((lane>>4)<<3));
          f32x4 d = MFMA16(a, bf_, fz);
          #pragma unroll
          for (int j = 0; j < 4; ++j){
            int q = mt*16 + (lane >> 4)*4 + j, key = ct*16 + (lane & 15);
            if (q < 56 && key < 56) scf[q*60 + key] = d[j] + p.rel_map[q*56 + key];
          }
        }
      }
      __syncthreads();
      // ---- softmax -> scb ----
      #pragma unroll
      for (int q = 0; q < 7; ++q){
        int r = wv*7 + q;
        float v = (lane < 56) ? scf[r*60 + lane] : -3.0e38f;
        float mx = wred_max(v);
        float e = (lane < 56) ? __expf(v - mx) : 0.f;
        float s = wred_sum(e);
        float a = e / s;
        scb[r*72 + lane] = (lane < 56) ? f2b(a) : (unsigned short)0;
        if (l == 3) awr[q] += a * 0.125f;
      }
      __syncthreads();
      // ---- PV ----
      {
        int ct = wv >> 2;
        f32x4 o = fz;
        #pragma unroll
        for (int ks = 0; ks < 2; ++ks){
          short8 a  = *(const short8*)(scb + (mt*16 + (lane&15))*72 + ks*32 + ((lane>>4)<<3));
          short8 bf_ = *(const short8*)(vT + (ct*16 + (lane&15))*72 + ks*32 + ((lane>>4)<<3));
          o = MFMA16(a, bf_, o);
        }
        #pragma unroll
        for (int j = 0; j < 4; ++j){
          int row = mt*16 + (lane >> 4)*4 + j;
          if (row < 56) oh[row*40 + ct*16 + (lane & 15)] = f2b(o[j]);
        }
      }
      // AO weight LDS write (loads arrived by now)
      *(short8*)(wst + t*8) = a0;
      *(short8*)(wst + (t+512)*8) = a1;
      __syncthreads();
      // ---- AO: po += oh @ Wo_h ----
      {
        short8 a = *(const short8*)(oh + (mt*16 + (lane&15))*40 + ((lane>>4)<<3));
        #pragma unroll
        for (int c = 0; c < 8; ++c){
          short8 bf_ = *(const short8*)(wst + (cg*8 + c)*512 + lane*8);
          po[c] = MFMA16(a, bf_, po[c]);
        }
      }
      __syncthreads();
    } // heads

    // residual + LN1
    addC_to_xs(xs, po, p.sa_bo + l*256, lane, wv);
    __syncthreads();
    ln_rows(xs, p.ln1_g + l*256, p.ln1_b + l*256, lane, wv);
    __syncthreads();

    // collapsed cross-attention
    if (t < 256){
      float a = p.ca_bkv[l*512 + 256 + t];
      const unsigned short* W = wsCAV + l*65536;
      for (int k = 0; k < 256; ++k) a = fmaf(condv[k], b2f(W[k*256 + t]), a);
      vcs[t] = a;
    }
    __syncthreads();
    if (t < 256){
      float a = p.ca_bo[l*256 + t];
      const unsigned short* W = wsCAO + l*65536;
      for (int k = 0; k < 256; ++k) a = fmaf(vcs[k], b2f(W[k*256 + t]), a);
      tmpf[t] = a;
    }
    __syncthreads();
    #pragma unroll
    for (int q = 0; q < 7; ++q){
      int r = wv*7 + q;
      #pragma unroll
      for (int u = 0; u < 4; ++u){ int n = lane + 64*u; xs[r*XSTR + n] += tmpf[n]; }
    }
    __syncthreads();
    ln_rows(xs, p.ln2_g + l*256, p.ln2_b + l*256, lane, wv);
    __syncthreads();
    build_afr(xs, afr, lane, mt);

    // FF: 4 chunks of 256 hidden
    {
      f32x4 po2[8];
      #pragma unroll
      for (int c = 0; c < 8; ++c) po2[c] = fz;
      const float* b1 = p.ff_b1 + l*1024;
      for (int ch = 0; ch < 4; ++ch){
        f32x4 fa[8];
        #pragma unroll
        for (int c = 0; c < 8; ++c) fa[c] = fz;
        gemm_pipe<true>(wsF1 + (size_t)(l*4 + ch)*65536, wst, afr, nullptr, fa, t, lane, mt, cg);
        #pragma unroll
        for (int c = 0; c < 8; ++c){
          int col = cg*128 + c*16 + (lane & 15);
          #pragma unroll
          for (int j = 0; j < 4; ++j){
            int row = mt*16 + (lane >> 4)*4 + j;
            if (row < 56) h1c[row*264 + col] = f2b(gelu_f(fa[c][j] + b1[ch*256 + col]));
          }
        }
        __syncthreads();
        gemm_pipe<false>(wsF2 + (size_t)(l*4 + ch)*65536, wst, nullptr, h1c, po2, t, lane, mt, cg);
      }
      addC_to_xs(xs, po2, p.ff_b2 + l*256, lane, wv);
      __syncthreads();
      ln_rows(xs, p.ln3_g + l*256, p.ln3_b + l*256, lane, wv);
      __syncthreads();
      build_afr(xs, afr, lane, mt);
    }
  } // layers

  // ---------------- attn_w ----------------
  if (lane < 56){
    #pragma unroll
    for (int q = 0; q < 7; ++q)
      p.out[OUT_AW + (size_t)b*3136 + (wv*7 + q)*56 + lane] = awr[q];
  }

  // ---------------- pose head ----------------
  {
    float pacc = 0.f;
    int mp = t / 6, op = t - mp*6;
    for (int ch = 0; ch < 4; ++ch){
      f32x4 pa[8];
      #pragma unroll
      for (int c = 0; c < 8; ++c) pa[c] = fz;
      gemm_pipe<true>(wsROT + (size_t)ch*65536, wst, afr, nullptr, pa, t, lane, mt, cg);
      #pragma unroll
      for (int c = 0; c < 8; ++c){
        int col = cg*128 + c*16 + (lane & 15);
        #pragma unroll
        for (int j = 0; j < 4; ++j){
          int row = mt*16 + (lane >> 4)*4 + j;
          if (row < 56) h1c[row*264 + col] = f2b(gelu_f(pa[c][j] + p.rot_b1[ch*256 + col]));
        }
      }
      __syncthreads();
      if (t < 330){
        for (int d = 0; d < 256; ++d)
          pacc = fmaf(b2f(h1c[mp*264 + d]), p.rot_W2[(size_t)(ch*256 + d)*6 + op], pacc);
      }
      __syncthreads();
    }
    if (t < 330) p.out[(size_t)b*330 + t] = pacc + p.rot_b2[op];
  }

  // ---------------- transl head ----------------
  {
    float* trf = (float*)(smem + R3);
    for (int c = t; c < 1024; c += Tc){
      float a = p.tr_b1[c];
      for (int k = 0; k < 256; ++k) a = fmaf(xs[55*XSTR + k], b2f(wsTR[k*1024 + c]), a);
      trf[c] = gelu_f(a);
    }
    __syncthreads();
    float part = 0.f;
    for (int c = t; c < 1024; c += Tc) part = fmaf(trf[c], p.tr_W2[c], part);
    part = wred_sum(part);
    if (lane == 0) vcs[wv] = part;
    __syncthreads();
    if (t == 0){
      float s = p.tr_b2[0];
      #pragma unroll
      for (int w2 = 0; w2 < 8; ++w2) s += vcs[w2];
      p.out[OUT_TR + b] = s;
    }
  }
}

extern "C" void kernel_launch(void* const* d_in, const int* in_sizes, int n_in,
                              void* d_out, int out_size, void* d_ws, size_t ws_size,
                              hipStream_t stream){
  (void)in_sizes; (void)n_in; (void)out_size; (void)ws_size;
  auto F = [&](int i) -> const float* { return (const float*)d_in[i]; };

  PP pp;
  pp.sa_Wqkv = F(20); pp.sa_Wo = F(22); pp.ff_W1 = F(30); pp.ff_W2 = F(32);
  pp.rot_W1 = F(40); pp.pose_W2 = F(5); pp.ca_Wkv = F(26); pp.ca_Wo = F(28);
  pp.cond_W2 = F(15); pp.tr_W1 = F(44);
  pp.wb = (unsigned short*)d_ws;
  hipLaunchKernelGGL(prep_kernel, dim3((WTOT + 255u)/256u), dim3(256), 0, stream, pp);

  KP p;
  p.bp = F(0); p.wrist = F(1); p.betas = F(2);
  p.pose_W1 = F(3); p.pose_b1 = F(4); p.pose_b2 = F(6);
  p.joints = F(7); p.mask_emb = F(8); p.transl_emb = F(9);
  p.in_g = F(10); p.in_b = F(11);
  p.gender_tab = F(12);
  p.cond_W1 = F(13); p.cond_b1 = F(14); p.cond_b2 = F(16);
  p.cond_g = F(17); p.cond_b = F(18);
  p.rel_map = F(19);
  p.sa_bqkv = F(21); p.sa_bo = F(23);
  p.ca_bkv = F(27); p.ca_bo = F(29);
  p.ff_b1 = F(31); p.ff_b2 = F(33);
  p.ln1_g = F(34); p.ln1_b = F(35); p.ln2_g = F(36); p.ln2_b = F(37);
  p.ln3_g = F(38); p.ln3_b = F(39);
  p.rot_b1 = F(41); p.rot_W2 = F(42); p.rot_b2 = F(43);
  p.tr_b1 = F(45); p.tr_W2 = F(46); p.tr_b2 = F(47);
  p.gender = (const int*)d_in[48]; p.mask_ids = (const int*)d_in[49];
  p.wb = (const unsigned short*)d_ws;
  p.out = (float*)d_out;

  hipLaunchKernelGGL(actor_kernel, dim3(Bc), dim3(Tc), 0, stream, p);
}

// Round 6
// 8314.233 us; speedup vs baseline: 2.8134x; 1.0744x over previous
//
#include <hip/hip_runtime.h>
#include <hip/hip_bf16.h>

#define DEV static __device__ __forceinline__

typedef __attribute__((ext_vector_type(8))) short short8;
typedef __attribute__((ext_vector_type(4))) float f32x4;
#define MFMA16(a,b,c) __builtin_amdgcn_mfma_f32_16x16x32_bf16(a,b,c,0,0,0)

constexpr int Bc = 2048, Tc = 1024;
constexpr int OUT_TR = 675840;
constexpr int OUT_AW = 677888;
constexpr int XSTR = 260;          // xs row stride (floats)

// ---- d_ws bf16 frag-linear layout (ushort offsets) ----
constexpr unsigned WQKV = 0;        // l4 x hp4 x ks8 x ct12 x 512 (q-scale folded)
constexpr unsigned WO   = 786432;   // l4 x ks8 x ct16 x 512
constexpr unsigned WF1  = 1048576;  // l4 x ch4 x ks8 x ct16 x 512
constexpr unsigned WF2  = 2097152;  // l4 x ch4(k) x ks8 x ct16 x 512
constexpr unsigned WROT = 3145728;  // ch4 x ks8 x ct16 x 512
constexpr unsigned WP2  = 3407872;  // ks8 x ct16 x 512
constexpr unsigned WTOT = 3473408;  // 6.95 MB

// ---- LDS map (bytes) ----
constexpr int XS   = 0;         // f32 [56][260]   58240
constexpr int XB   = 58240;     // u16 [56][264]   29568
constexpr int QP   = 87808;     // u16 [2][56][40]  8960
constexpr int KP_  = 96768;     // u16 [2][56][40]  8960
constexpr int VTP  = 105728;    // u16 [2][32][72]  9216
constexpr int OH   = 114944;    // u16 [56][264]   29568  (oh / h1c / parts / tmpf / trf)
constexpr int SCB  = 144512;    // u16 [56][72]     8064  (also bpf float stage)
constexpr int CONDV= 152576;    // f32 [256]
constexpr int VCS  = 153600;    // f32 [256]
constexpr int SMEM_TOT = 154624;

struct PP {
  const float *sa_Wqkv,*sa_Wo,*ff_W1,*ff_W2,*rot_W1,*pose_W2;
  unsigned short* wb;
};
struct KP {
  const float *bp,*wrist,*betas;
  const float *pose_W1,*pose_b1,*pose_b2;
  const float *joints,*mask_emb,*transl_emb,*in_g,*in_b;
  const float *gender_tab,*cond_W1,*cond_b1,*cond_W2,*cond_b2,*cond_g,*cond_b;
  const float *rel_map;
  const float *sa_bqkv,*sa_bo;
  const float *ca_Wkv,*ca_bkv,*ca_Wo,*ca_bo;
  const float *ff_b1,*ff_b2;
  const float *ln1_g,*ln1_b,*ln2_g,*ln2_b,*ln3_g,*ln3_b;
  const float *rot_b1,*rot_W2,*rot_b2;
  const float *tr_W1,*tr_b1,*tr_W2,*tr_b2;
  const int *gender,*mask_ids;
  const unsigned short* wb;
  float* out;
};

DEV unsigned short f2b(float x){
  union { __hip_bfloat16 h; unsigned short u; } c; c.h = __float2bfloat16(x); return c.u;
}
DEV float b2f(unsigned short u){
  union { __hip_bfloat16 h; unsigned short u; } c; c.u = u; return __bfloat162float(c.h);
}
DEV float gelu_f(float x){
  float z = 0.7978845608028654f * (x + 0.044715f * x * x * x);
  return x / (1.0f + __expf(-2.0f * z));
}
DEV float wred_sum(float v){
  #pragma unroll
  for (int m = 32; m; m >>= 1) v += __shfl_xor(v, m, 64);
  return v;
}
DEV float wred_max(float v){
  #pragma unroll
  for (int m = 32; m; m >>= 1) v = fmaxf(v, __shfl_xor(v, m, 64));
  return v;
}
DEV int rcl(int r){ return r > 55 ? 55 : r; }   // A-row clamp (rows>55 produce discarded C rows)

// ================= prep: fp32 weights -> bf16 fragment-linear =================
__global__ __launch_bounds__(256)
void prep_kernel(PP a){
  unsigned i = blockIdx.x*256u + threadIdx.x;
  if (i >= WTOT) return;
  float v;
  if (i < WO){                                   // WQKV (N=192 per head-pair)
    unsigned l=i/196608u, r=i%196608u, hp=r/49152u, r2=r%49152u;
    unsigned ks=r2/6144u, r3=r2%6144u, ct=r3/512u, r4=r3&511u;
    unsigned lane=r4>>3, e=r4&7u;
    unsigned c192=ct*16u+(lane&15u), k=ks*32u+((lane>>4)<<3)+e;
    unsigned part=c192>>6, hh=(c192>>5)&1u, d=c192&31u;
    v = a.sa_Wqkv[l*196608u + k*768u + part*256u + (hp*2u+hh)*32u + d];
    if (part==0u) v *= 0.17677669529663687f;
  } else if (i < WF1){                           // WO (K=256 over head-concat)
    unsigned j=i-WO, l=j/65536u, r=j%65536u, ks=r/8192u, r3=r%8192u;
    unsigned ct=r3/512u, r4=r3&511u, lane=r4>>3, e=r4&7u;
    unsigned col=ct*16u+(lane&15u), k=ks*32u+((lane>>4)<<3)+e;
    v = a.sa_Wo[l*65536u + k*256u + col];
  } else if (i < WF2){                           // WF1 chunk-N256
    unsigned j=i-WF1, l=j/262144u, r=j%262144u, ch=r/65536u, r2=r%65536u;
    unsigned ks=r2/8192u, r3=r2%8192u, ct=r3/512u, r4=r3&511u, lane=r4>>3, e=r4&7u;
    unsigned col=ct*16u+(lane&15u), k=ks*32u+((lane>>4)<<3)+e;
    v = a.ff_W1[l*262144u + k*1024u + ch*256u + col];
  } else if (i < WROT){                          // WF2 chunk-K256
    unsigned j=i-WF2, l=j/262144u, r=j%262144u, ch=r/65536u, r2=r%65536u;
    unsigned ks=r2/8192u, r3=r2%8192u, ct=r3/512u, r4=r3&511u, lane=r4>>3, e=r4&7u;
    unsigned col=ct*16u+(lane&15u), k=ks*32u+((lane>>4)<<3)+e;
    v = a.ff_W2[l*262144u + (ch*256u+k)*256u + col];
  } else if (i < WP2){                           // WROT
    unsigned j=i-WROT, ch=j/65536u, r2=j%65536u;
    unsigned ks=r2/8192u, r3=r2%8192u, ct=r3/512u, r4=r3&511u, lane=r4>>3, e=r4&7u;
    unsigned col=ct*16u+(lane&15u), k=ks*32u+((lane>>4)<<3)+e;
    v = a.rot_W1[k*1024u + ch*256u + col];
  } else {                                       // WP2
    unsigned j=i-WP2, ks=j/8192u, r3=j%8192u;
    unsigned ct=r3/512u, r4=r3&511u, lane=r4>>3, e=r4&7u;
    unsigned col=ct*16u+(lane&15u), k=ks*32u+((lane>>4)<<3)+e;
    v = a.pose_W2[k*256u + col];
  }
  a.wb[i] = f2b(v);
}

// ================= main helpers =================
// wave computes 4 m-tiles x 1 ct (16 cols) x K=256. B direct from global, A from LDS.
DEV void gemm_ct(const unsigned short* A, const unsigned short* Bg, int ct, int nct,
                 f32x4* C, int lane){
  short8 bfr[8];
  #pragma unroll
  for (int ks = 0; ks < 8; ++ks)
    bfr[ks] = *(const short8*)(Bg + (ks*nct + ct)*512 + lane*8);
  #pragma unroll
  for (int ks = 0; ks < 8; ++ks){
    #pragma unroll
    for (int m = 0; m < 4; ++m){
      short8 a = *(const short8*)(A + rcl(m*16 + (lane&15))*264 + ks*32 + ((lane>>4)<<3));
      C[m] = MFMA16(a, bfr[ks], C[m]);
    }
  }
}

// LN rows w*4..w*4+3 (waves 0..13), optional bf16 mirror
DEV void ln16(float* xs, unsigned short* xb, const float* g, const float* bta,
              int lane, int wv, bool wxb){
  if (wv >= 14) return;
  #pragma unroll
  for (int q = 0; q < 4; ++q){
    int r = wv*4 + q;
    float v[4]; float s = 0.f, s2 = 0.f;
    #pragma unroll
    for (int u = 0; u < 4; ++u){ v[u] = xs[r*XSTR + lane + 64*u]; s += v[u]; s2 = fmaf(v[u], v[u], s2); }
    s = wred_sum(s); s2 = wred_sum(s2);
    float mean = s * (1.f/256.f);
    float var  = s2 * (1.f/256.f) - mean*mean;
    float rs = rsqrtf(var + 1e-5f);
    #pragma unroll
    for (int u = 0; u < 4; ++u){
      int n = lane + 64*u;
      float o = (v[u]-mean)*rs*g[n] + bta[n];
      xs[r*XSTR + n] = o;
      if (wxb) xb[r*264 + n] = f2b(o);
    }
  }
}

// add 4 C-frags (wave's 16-col slice) + bias into xs
DEV void addC(float* xs, const f32x4* C, const float* bias, int lane, int wv){
  int col = wv*16 + (lane & 15);
  #pragma unroll
  for (int m = 0; m < 4; ++m){
    #pragma unroll
    for (int j = 0; j < 4; ++j){
      int row = m*16 + (lane >> 4)*4 + j;
      if (row < 56) xs[row*XSTR + col] += C[m][j] + bias[col];
    }
  }
}

__global__ __launch_bounds__(Tc)
void actor_kernel(KP p){
  __shared__ __align__(16) char smem[SMEM_TOT];
  float* xs    = (float*)(smem + XS);
  unsigned short* xb  = (unsigned short*)(smem + XB);
  unsigned short* qp  = (unsigned short*)(smem + QP);
  unsigned short* kp  = (unsigned short*)(smem + KP_);
  unsigned short* vtp = (unsigned short*)(smem + VTP);
  unsigned short* oh  = (unsigned short*)(smem + OH);   // also h1c
  unsigned short* scb = (unsigned short*)(smem + SCB);
  float* condv = (float*)(smem + CONDV);
  float* vcs   = (float*)(smem + VCS);
  float* parts = (float*)(smem + OH);          // [4][256] GEMV partials
  float* ocv   = (float*)(smem + OH) + 1024;   // [256]
  float* tmpf  = (float*)(smem + OH) + 2048;   // [512] cond hidden
  float* bpf   = (float*)(smem + SCB);         // [330] body_pose stage
  float* trf   = (float*)(smem + OH);          // [1024] transl hidden

  const int t = threadIdx.x;
  const int lane = t & 63, wv = t >> 6;
  const int b = blockIdx.x;
  const f32x4 fz = {0.f,0.f,0.f,0.f};
  float awr[4] = {0.f,0.f,0.f,0.f};

  // ---------------- stage cond input + body_pose ----------------
  if (t < 29){
    float v;
    if (t < 10) v = p.wrist[b*10 + t];
    else if (t < 13) v = p.betas[b*3 + (t-10)];
    else { int g = p.gender[b]; v = p.gender_tab[g*16 + (t-13)]; }
    vcs[t] = v;
  }
  if (t < 330) bpf[t] = p.bp[b*330 + t];
  __syncthreads();

  // cond W1 (29->512)
  if (t < 512){
    float a = p.cond_b1[t];
    #pragma unroll 1
    for (int k = 0; k < 29; ++k) a = fmaf(vcs[k], p.cond_W1[k*512 + t], a);
    tmpf[t] = gelu_f(a);
  }
  __syncthreads();
  // cond W2 (512->256), 4-way split
  {
    int col = t & 255, pg = t >> 8;
    float a = 0.f;
    const float* W = p.cond_W2 + col;
    for (int k = pg*128; k < pg*128 + 128; ++k) a = fmaf(tmpf[k], W[(size_t)k*256], a);
    parts[pg*256 + col] = a;
  }
  __syncthreads();
  if (t < 256) condv[t] = p.cond_b2[t] + parts[t] + parts[256+t] + parts[512+t] + parts[768+t];
  __syncthreads();
  // cond LN (wave 0) + embed W1 GEMV (all) in parallel
  if (wv == 0){
    float v[4], s = 0.f, s2 = 0.f;
    #pragma unroll
    for (int u = 0; u < 4; ++u){ v[u] = condv[lane + 64*u]; s += v[u]; s2 = fmaf(v[u], v[u], s2); }
    s = wred_sum(s); s2 = wred_sum(s2);
    float mean = s * (1.f/256.f);
    float var  = s2 * (1.f/256.f) - mean*mean;
    float rs = rsqrtf(var + 1e-5f);
    #pragma unroll
    for (int u = 0; u < 4; ++u){ int n = lane + 64*u; condv[n] = (v[u]-mean)*rs*p.cond_g[n] + p.cond_b[n]; }
  }
  // NOTE: embed writes oh (overlaps parts) -> must come AFTER condv reduce barrier; condv LN touches condv only.
  {
    int n = t & 255, mb = t >> 8;
    for (int m = mb; m < 55; m += 4){
      float a = p.pose_b1[n];
      #pragma unroll
      for (int k = 0; k < 6; ++k) a = fmaf(bpf[m*6 + k], p.pose_W1[k*256 + n], a);
      oh[m*264 + n] = f2b(gelu_f(a));
    }
    if (t < 256) oh[55*264 + t] = 0;
  }
  __syncthreads();

  // embed GEMM: x = h1 @ pose_W2 (+emb fixup) -> xs
  {
    f32x4 acc[4] = {fz,fz,fz,fz};
    gemm_ct(oh, p.wb + WP2, wv, 16, acc, lane);
    int col = wv*16 + (lane & 15);
    #pragma unroll
    for (int m = 0; m < 4; ++m){
      #pragma unroll
      for (int j = 0; j < 4; ++j){
        int row = m*16 + (lane >> 4)*4 + j;
        if (row < 56){
          float v = (row < 55) ? (acc[m][j] + p.pose_b2[col]) : p.transl_emb[col];
          v = p.mask_ids[b*56 + row] ? v : p.mask_emb[col];
          v += p.joints[row*256 + col];
          xs[row*XSTR + col] = v;
        }
      }
    }
    __syncthreads();
    ln16(xs, xb, p.in_g, p.in_b, lane, wv, true);
    __syncthreads();
  }

  // ---------------- layers ----------------
  for (int l = 0; l < 4; ++l){
    const float* bqkv = p.sa_bqkv + l*768;

    for (int hp = 0; hp < 4; ++hp){
      // zero vT key-pads (56..63) both heads
      if (t < 512) vtp[(t>>8)*2304 + ((t&255)>>3)*72 + 56 + (t&7)] = 0;
      // QKV pair GEMM (N=192): waves 0..11
      if (wv < 12){
        f32x4 aq[4] = {fz,fz,fz,fz};
        gemm_ct(xb, p.wb + WQKV + (size_t)(l*4 + hp)*49152, wv, 12, aq, lane);
        int c192 = wv*16 + (lane & 15);
        int part = c192 >> 6, hh = (c192 >> 5) & 1, d = c192 & 31;
        float bias = bqkv[part*256 + (hp*2 + hh)*32 + d];
        if (part == 0) bias *= 0.17677669529663687f;
        #pragma unroll
        for (int m = 0; m < 4; ++m){
          #pragma unroll
          for (int j = 0; j < 4; ++j){
            int row = m*16 + (lane >> 4)*4 + j;
            if (row < 56){
              float v = aq[m][j] + bias;
              if (part == 0)      qp[hh*2240 + row*40 + d] = f2b(v);
              else if (part == 1) kp[hh*2240 + row*40 + d] = f2b(v);
              else                vtp[hh*2304 + d*72 + row] = f2b(v);
            }
          }
        }
      }
      __syncthreads();

      for (int hh = 0; hh < 2; ++hh){
        // scores: 16 tiles (4m x 4n), 1 per wave, K=32
        {
          int m = wv >> 2, n = wv & 3;
          short8 a  = *(const short8*)(qp + hh*2240 + rcl(m*16 + (lane&15))*40 + ((lane>>4)<<3));
          short8 bf_= *(const short8*)(kp + hh*2240 + rcl(n*16 + (lane&15))*40 + ((lane>>4)<<3));
          f32x4 d = MFMA16(a, bf_, fz);
          #pragma unroll
          for (int j = 0; j < 4; ++j){
            int row = m*16 + (lane >> 4)*4 + j, col = n*16 + (lane & 15);
            if (row < 56 && col < 56)
              scb[row*72 + col] = f2b(d[j] + p.rel_map[row*56 + col]);
          }
        }
        __syncthreads();
        // softmax rows w*4+q (waves 0..13); zero K-pad cols 56..63
        if (wv < 14){
          #pragma unroll
          for (int q = 0; q < 4; ++q){
            int r = wv*4 + q;
            float v = (lane < 56) ? b2f(scb[r*72 + lane]) : -3.0e38f;
            float mx = wred_max(v);
            float e = (lane < 56) ? __expf(v - mx) : 0.f;
            float s = wred_sum(e);
            float a = e / s;
            if (lane < 64) scb[r*72 + lane] = (lane < 56) ? f2b(a) : (unsigned short)0;
            if (l == 3) awr[q] += a * 0.125f;
          }
        }
        __syncthreads();
        // PV: 8 tiles (4m x 2dt), waves 0..7, K=64
        if (wv < 8){
          int m = wv >> 1, dt = wv & 1;
          f32x4 o = fz;
          #pragma unroll
          for (int ks = 0; ks < 2; ++ks){
            short8 a  = *(const short8*)(scb + rcl(m*16 + (lane&15))*72 + ks*32 + ((lane>>4)<<3));
            short8 bf_= *(const short8*)(vtp + hh*2304 + (dt*16 + (lane&15))*72 + ks*32 + ((lane>>4)<<3));
            o = MFMA16(a, bf_, o);
          }
          int h = hp*2 + hh;
          #pragma unroll
          for (int j = 0; j < 4; ++j){
            int row = m*16 + (lane >> 4)*4 + j;
            if (row < 56) oh[row*264 + h*32 + dt*16 + (lane & 15)] = f2b(o[j]);
          }
        }
        __syncthreads();
      }
    } // head pairs

    // AO: po = oh @ Wo (K=256 over all heads), then residual+LN1
    {
      f32x4 po[4] = {fz,fz,fz,fz};
      gemm_ct(oh, p.wb + WO + (size_t)l*65536, wv, 16, po, lane);
      addC(xs, po, p.sa_bo + l*256, lane, wv);
    }
    __syncthreads();
    ln16(xs, nullptr, p.ln1_g + l*256, p.ln1_b + l*256, lane, wv, false);
    __syncthreads();

    // collapsed cross-attn: vc = cond @ Wkv_v + b ; ocp = vc @ Wo + b (4-way split GEMVs)
    {
      int col = t & 255, pg = t >> 8;
      float a = 0.f;
      const float* W = p.ca_Wkv + (size_t)l*131072 + 256 + col;
      for (int k = pg*64; k < pg*64 + 64; ++k) a = fmaf(condv[k], W[(size_t)k*512], a);
      parts[pg*256 + col] = a;
    }
    __syncthreads();
    if (t < 256) vcs[t] = p.ca_bkv[l*512 + 256 + t] + parts[t] + parts[256+t] + parts[512+t] + parts[768+t];
    __syncthreads();
    {
      int col = t & 255, pg = t >> 8;
      float a = 0.f;
      const float* W = p.ca_Wo + (size_t)l*65536 + col;
      for (int k = pg*64; k < pg*64 + 64; ++k) a = fmaf(vcs[k], W[(size_t)k*256], a);
      parts[pg*256 + col] = a;   // note: overwrites; vcs already consumed? no -> read done this pass
    }
    __syncthreads();
    if (t < 256) ocv[t] = p.ca_bo[l*256 + t] + parts[t] + parts[256+t] + parts[512+t] + parts[768+t];
    __syncthreads();
    if (wv < 14){
      #pragma unroll
      for (int q = 0; q < 4; ++q){
        int r = wv*4 + q;
        #pragma unroll
        for (int u = 0; u < 4; ++u){ int n = lane + 64*u; xs[r*XSTR + n] += ocv[n]; }
      }
    }
    ln16(xs, xb, p.ln2_g + l*256, p.ln2_b + l*256, lane, wv, true);
    __syncthreads();

    // FF: 4 chunks of 256 hidden
    {
      f32x4 po2[4] = {fz,fz,fz,fz};
      const float* b1 = p.ff_b1 + l*1024;
      for (int ch = 0; ch < 4; ++ch){
        f32x4 fa[4] = {fz,fz,fz,fz};
        gemm_ct(xb, p.wb + WF1 + (size_t)(l*4 + ch)*65536, wv, 16, fa, lane);
        int col = wv*16 + (lane & 15);
        #pragma unroll
        for (int m = 0; m < 4; ++m){
          #pragma unroll
          for (int j = 0; j < 4; ++j){
            int row = m*16 + (lane >> 4)*4 + j;
            if (row < 56) oh[row*264 + col] = f2b(gelu_f(fa[m][j] + b1[ch*256 + col]));
          }
        }
        __syncthreads();
        gemm_ct(oh, p.wb + WF2 + (size_t)(l*4 + ch)*65536, wv, 16, po2, lane);
        __syncthreads();
      }
      addC(xs, po2, p.ff_b2 + l*256, lane, wv);
      __syncthreads();
      ln16(xs, xb, p.ln3_g + l*256, p.ln3_b + l*256, lane, wv, true);
      __syncthreads();
    }
  } // layers

  // ---------------- attn_w ----------------
  if (wv < 14 && lane < 56){
    #pragma unroll
    for (int q = 0; q < 4; ++q)
      p.out[OUT_AW + (size_t)b*3136 + (wv*4 + q)*56 + lane] = awr[q];
  }

  // ---------------- pose head ----------------
  {
    float pacc = 0.f;
    int mp = t / 6, op = t - mp*6;
    for (int ch = 0; ch < 4; ++ch){
      f32x4 pa[4] = {fz,fz,fz,fz};
      gemm_ct(xb, p.wb + WROT + (size_t)ch*65536, wv, 16, pa, lane);
      int col = wv*16 + (lane & 15);
      #pragma unroll
      for (int m = 0; m < 4; ++m){
        #pragma unroll
        for (int j = 0; j < 4; ++j){
          int row = m*16 + (lane >> 4)*4 + j;
          if (row < 56) oh[row*264 + col] = f2b(gelu_f(pa[m][j] + p.rot_b1[ch*256 + col]));
        }
      }
      __syncthreads();
      if (t < 330){
        for (int d = 0; d < 256; ++d)
          pacc = fmaf(b2f(oh[mp*264 + d]), p.rot_W2[(size_t)(ch*256 + d)*6 + op], pacc);
      }
      __syncthreads();
    }
    if (t < 330) p.out[(size_t)b*330 + t] = pacc + p.rot_b2[op];
  }

  // ---------------- transl head ----------------
  {
    float a = p.tr_b1[t];
    for (int k = 0; k < 256; ++k) a = fmaf(xs[55*XSTR + k], p.tr_W1[(size_t)k*1024 + t], a);
    trf[t] = gelu_f(a);
    __syncthreads();
    float part = trf[t] * p.tr_W2[t];
    part = wred_sum(part);
    if (lane == 0) vcs[wv] = part;
    __syncthreads();
    if (t == 0){
      float s = p.tr_b2[0];
      #pragma unroll
      for (int w2 = 0; w2 < 16; ++w2) s += vcs[w2];
      p.out[OUT_TR + b] = s;
    }
  }
}

extern "C" void kernel_launch(void* const* d_in, const int* in_sizes, int n_in,
                              void* d_out, int out_size, void* d_ws, size_t ws_size,
                              hipStream_t stream){
  (void)in_sizes; (void)n_in; (void)out_size; (void)ws_size;
  auto F = [&](int i) -> const float* { return (const float*)d_in[i]; };

  PP pp;
  pp.sa_Wqkv = F(20); pp.sa_Wo = F(22); pp.ff_W1 = F(30); pp.ff_W2 = F(32);
  pp.rot_W1 = F(40); pp.pose_W2 = F(5);
  pp.wb = (unsigned short*)d_ws;
  hipLaunchKernelGGL(prep_kernel, dim3((WTOT + 255u)/256u), dim3(256), 0, stream, pp);

  KP p;
  p.bp = F(0); p.wrist = F(1); p.betas = F(2);
  p.pose_W1 = F(3); p.pose_b1 = F(4); p.pose_b2 = F(6);
  p.joints = F(7); p.mask_emb = F(8); p.transl_emb = F(9);
  p.in_g = F(10); p.in_b = F(11);
  p.gender_tab = F(12);
  p.cond_W1 = F(13); p.cond_b1 = F(14); p.cond_W2 = F(15); p.cond_b2 = F(16);
  p.cond_g = F(17); p.cond_b = F(18);
  p.rel_map = F(19);
  p.sa_bqkv = F(21); p.sa_bo = F(23);
  p.ca_Wkv = F(26); p.ca_bkv = F(27); p.ca_Wo = F(28); p.ca_bo = F(29);
  p.ff_b1 = F(31); p.ff_b2 = F(33);
  p.ln1_g = F(34); p.ln1_b = F(35); p.ln2_g = F(36); p.ln2_b = F(37);
  p.ln3_g = F(38); p.ln3_b = F(39);
  p.rot_b1 = F(41); p.rot_W2 = F(42); p.rot_b2 = F(43);
  p.tr_W1 = F(44); p.tr_b1 = F(45); p.tr_W2 = F(46); p.tr_b2 = F(47);
  p.gender = (const int*)d_in[48]; p.mask_ids = (const int*)d_in[49];
  p.wb = (const unsigned short*)d_ws;
  p.out = (float*)d_out;

  hipLaunchKernelGGL(actor_kernel, dim3(Bc), dim3(Tc), 0, stream, p);
}

// Round 8
// 6804.395 us; speedup vs baseline: 3.4376x; 1.2219x over previous
//
#include <hip/hip_runtime.h>
#include <hip/hip_bf16.h>

#define DEV static __device__ __forceinline__

typedef __attribute__((ext_vector_type(8))) short short8;
typedef __attribute__((ext_vector_type(4))) float f32x4;
#define MFMA16(a,b,c) __builtin_amdgcn_mfma_f32_16x16x32_bf16(a,b,c,0,0,0)

constexpr int Tc = 1024;
constexpr int NB = 1024;              // blocks; 2 batch elems each
constexpr int OUT_TR = 675840;
constexpr int OUT_AW = 677888;

// ---- d_ws bf16 frag-linear (u16 offsets) ----
constexpr unsigned WQKV = 0;          // l4 x hp4 x ks8 x ct12 x 512 (q-scale folded)
constexpr unsigned WO   = 786432;     // l4 x h8 x ct16 x 512   (K=32 per head)
constexpr unsigned WF1  = 1048576;    // l4 x ch4 x ks8 x ct16 x 512
constexpr unsigned WF2  = 2097152;    // l4 x ch4(k) x ks8 x ct16 x 512
constexpr unsigned WROT = 3145728;    // ch4 x ks8 x ct16 x 512
constexpr unsigned WP2  = 3407872;    // ks8 x ct16 x 512
constexpr unsigned WTOT = 3473408;

// ---- LDS (bytes) ----
constexpr int XB0 = 0;                // u16 [56][264]
constexpr int XB1 = 29568;
constexpr int ATT = 59136;            // 79360-byte arena
constexpr int STATS = 138496;         // f32 [2][128] (mean|rstd)
constexpr int CONDV = 140544;         // f32 [2][256]
constexpr int X55  = 142592;          // f32 [2][256] (also condin)
constexpr int SMEM_TOT = 144640;

// u16 offsets in arena
constexpr int ATTe = ATT/2;
constexpr int QPo  = ATTe;            // (e*2+hh)*2240 + row*40 + d
constexpr int KPo  = ATTe + 8960;
constexpr int VTo  = ATTe + 17920;    // (e*2+hh)*2304 + d*72 + row
constexpr int SCBo = ATTe + 27136;    // e*4032 + row*72 + key   (FIX: was e*8064, collided with OHo)
constexpr int SCST = 4032;
constexpr int OHo  = ATTe + 35200;    // e*2240 + row*40 + d  (= SCBo + 2*4032, packs exactly)
// f32 indices (into (float*)smem)
constexpr int PARTS_S  = 14784;       // [2][16][64]
constexpr int PARTS_S2 = 16832;
constexpr int PARTSGf  = 14784;       // GEMV partials [2][2][256]
constexpr int VCSBf    = 15808;
constexpr int OCVf     = 16320;
constexpr int TMPFf    = 16832;       // cond hidden [2][512]
constexpr int BPFf     = 29568;       // body_pose stage [2][330]
constexpr int TRFf     = 14784;       // transl hidden [2][1024]
constexpr int STATSf   = 34624;
constexpr int WSUMf    = 34624;
constexpr int CONDVf   = 35136;
constexpr int X55f     = 35648;

struct PP {
  const float *sa_Wqkv,*sa_Wo,*ff_W1,*ff_W2,*rot_W1,*pose_W2;
  unsigned short* wb;
};
struct KP {
  const float *bp,*wrist,*betas;
  const float *pose_W1,*pose_b1,*pose_b2;
  const float *joints,*mask_emb,*transl_emb,*in_g,*in_b;
  const float *gender_tab,*cond_W1,*cond_b1,*cond_W2,*cond_b2,*cond_g,*cond_b;
  const float *rel_map;
  const float *sa_bqkv,*sa_bo;
  const float *ca_Wkv,*ca_bkv,*ca_Wo,*ca_bo;
  const float *ff_b1,*ff_b2;
  const float *ln1_g,*ln1_b,*ln2_g,*ln2_b,*ln3_g,*ln3_b;
  const float *rot_b1,*rot_W2,*rot_b2;
  const float *tr_W1,*tr_b1,*tr_W2,*tr_b2;
  const int *gender,*mask_ids;
  const unsigned short* wb;
  float* out;
};

DEV unsigned short f2b(float x){
  union { __hip_bfloat16 h; unsigned short u; } c; c.h = __float2bfloat16(x); return c.u;
}
DEV float b2f(unsigned short u){
  union { __hip_bfloat16 h; unsigned short u; } c; c.u = u; return __bfloat162float(c.h);
}
DEV float gelu_f(float x){
  float z = 0.7978845608028654f * (x + 0.044715f * x * x * x);
  return x / (1.0f + __expf(-2.0f * z));
}
DEV float wred_sum(float v){
  #pragma unroll
  for (int m = 32; m; m >>= 1) v += __shfl_xor(v, m, 64);
  return v;
}
DEV float wred_max(float v){
  #pragma unroll
  for (int m = 32; m; m >>= 1) v = fmaxf(v, __shfl_xor(v, m, 64));
  return v;
}
DEV int rcl(int r){ return r > 55 ? 55 : r; }

// ================= prep =================
__global__ __launch_bounds__(256)
void prep_kernel(PP a){
  unsigned i = blockIdx.x*256u + threadIdx.x;
  if (i >= WTOT) return;
  float v;
  if (i < WO){                                   // WQKV
    unsigned l=i/196608u, r=i%196608u, hp=r/49152u, r2=r%49152u;
    unsigned ks=r2/6144u, r3=r2%6144u, ct=r3/512u, r4=r3&511u;
    unsigned lane=r4>>3, e=r4&7u;
    unsigned c192=ct*16u+(lane&15u), k=ks*32u+((lane>>4)<<3)+e;
    unsigned part=c192>>6, hh=(c192>>5)&1u, d=c192&31u;
    v = a.sa_Wqkv[l*196608u + k*768u + part*256u + (hp*2u+hh)*32u + d];
    if (part==0u) v *= 0.17677669529663687f;
  } else if (i < WF1){                           // WO per-head K=32
    unsigned j=i-WO, l=j/65536u, r=j%65536u, h=r/8192u, r2=r%8192u;
    unsigned ct=r2/512u, r4=r2&511u, lane=r4>>3, e=r4&7u;
    unsigned col=ct*16u+(lane&15u), k=((lane>>4)<<3)+e;
    v = a.sa_Wo[l*65536u + (h*32u+k)*256u + col];
  } else if (i < WF2){                           // WF1
    unsigned j=i-WF1, l=j/262144u, r=j%262144u, ch=r/65536u, r2=r%65536u;
    unsigned ks=r2/8192u, r3=r2%8192u, ct=r3/512u, r4=r3&511u, lane=r4>>3, e=r4&7u;
    unsigned col=ct*16u+(lane&15u), k=ks*32u+((lane>>4)<<3)+e;
    v = a.ff_W1[l*262144u + k*1024u + ch*256u + col];
  } else if (i < WROT){                          // WF2
    unsigned j=i-WF2, l=j/262144u, r=j%262144u, ch=r/65536u, r2=r%65536u;
    unsigned ks=r2/8192u, r3=r2%8192u, ct=r3/512u, r4=r3&511u, lane=r4>>3, e=r4&7u;
    unsigned col=ct*16u+(lane&15u), k=ks*32u+((lane>>4)<<3)+e;
    v = a.ff_W2[l*262144u + (ch*256u+k)*256u + col];
  } else if (i < WP2){                           // WROT
    unsigned j=i-WROT, ch=j/65536u, r2=j%65536u;
    unsigned ks=r2/8192u, r3=r2%8192u, ct=r3/512u, r4=r3&511u, lane=r4>>3, e=r4&7u;
    unsigned col=ct*16u+(lane&15u), k=ks*32u+((lane>>4)<<3)+e;
    v = a.rot_W1[k*1024u + ch*256u + col];
  } else {                                       // WP2
    unsigned j=i-WP2, ks=j/8192u, r3=j%8192u;
    unsigned ct=r3/512u, r4=r3&511u, lane=r4>>3, e=r4&7u;
    unsigned col=ct*16u+(lane&15u), k=ks*32u+((lane>>4)<<3)+e;
    v = a.pose_W2[k*256u + col];
  }
  a.wb[i] = f2b(v);
}

// ================= helpers =================
// E=2 GEMM: B frag-linear from global (shared), A0/A1 bf16 LDS (stride astr)
DEV void gemm2(const unsigned short* su, int a0o, int a1o, int astr,
               const unsigned short* Bg, int ct, int nct,
               f32x4* C0, f32x4* C1, int lane){
  short8 b[8];
  #pragma unroll
  for (int ks = 0; ks < 8; ++ks)
    b[ks] = *(const short8*)(Bg + (size_t)(ks*nct + ct)*512 + lane*8);
  #pragma unroll
  for (int ks = 0; ks < 8; ++ks){
    #pragma unroll
    for (int m = 0; m < 4; ++m){
      short8 a0 = *(const short8*)(su + a0o + rcl(m*16 + (lane&15))*astr + ks*32 + ((lane>>4)<<3));
      C0[m] = MFMA16(a0, b[ks], C0[m]);
      short8 a1 = *(const short8*)(su + a1o + rcl(m*16 + (lane&15))*astr + ks*32 + ((lane>>4)<<3));
      C1[m] = MFMA16(a1, b[ks], C1[m]);
    }
  }
}

__global__ __launch_bounds__(Tc, 4)
void actor_kernel(KP p){
  __shared__ __align__(16) char smem[SMEM_TOT];
  float* sf = (float*)smem;
  unsigned short* su = (unsigned short*)smem;

  const int t = threadIdx.x;
  const int lane = t & 63, wv = t >> 6;
  const int hi = lane >> 4;
  const int col = wv*16 + (lane & 15);
  const int b2 = blockIdx.x * 2;
  const int eh = t >> 9, tt = t & 511;   // elem-half split
  const f32x4 fz = {0.f,0.f,0.f,0.f};

  f32x4 xsr[2][4];                       // x fp32 resident in regs (16-col slice)
  float awr[7] = {0,0,0,0,0,0,0};

  // ---- LN over reg-x: 2(+1 if wxb) barriers ----
  auto ln_regs = [&](const float* g, const float* bta, bool wxb){
    #pragma unroll
    for (int e = 0; e < 2; ++e){
      #pragma unroll
      for (int m = 0; m < 4; ++m){
        #pragma unroll
        for (int j = 0; j < 4; ++j){
          float s = xsr[e][m][j], s2 = s*s;
          #pragma unroll
          for (int mk = 1; mk < 16; mk <<= 1){
            s += __shfl_xor(s, mk, 64); s2 += __shfl_xor(s2, mk, 64);
          }
          if ((lane & 15) == 0){
            int row = m*16 + hi*4 + j;
            sf[PARTS_S  + (e*16 + wv)*64 + row] = s;
            sf[PARTS_S2 + (e*16 + wv)*64 + row] = s2;
          }
        }
      }
    }
    __syncthreads();
    if (t < 128){
      int e = t >> 6, row = t & 63;
      float s = 0.f, s2 = 0.f;
      #pragma unroll
      for (int w = 0; w < 16; ++w){
        s  += sf[PARTS_S  + (e*16 + w)*64 + row];
        s2 += sf[PARTS_S2 + (e*16 + w)*64 + row];
      }
      float mean = s * (1.f/256.f);
      float var  = s2 * (1.f/256.f) - mean*mean;
      sf[STATSf + e*128 + row]      = mean;
      sf[STATSf + e*128 + 64 + row] = rsqrtf(var + 1e-5f);
    }
    __syncthreads();
    float gg = g[col], bb = bta[col];
    #pragma unroll
    for (int e = 0; e < 2; ++e){
      int xbo = (e ? XB1 : XB0) / 2;
      #pragma unroll
      for (int m = 0; m < 4; ++m){
        #pragma unroll
        for (int j = 0; j < 4; ++j){
          int row = m*16 + hi*4 + j;
          float mean = sf[STATSf + e*128 + row];
          float rstd = sf[STATSf + e*128 + 64 + row];
          float o = (xsr[e][m][j] - mean) * rstd * gg + bb;
          xsr[e][m][j] = o;
          if (wxb && row < 56) su[xbo + row*264 + col] = f2b(o);
        }
      }
    }
    if (wxb) __syncthreads();
  };

  // ================= prologue =================
  if (tt < 29){
    float v;
    if (tt < 10) v = p.wrist[(b2+eh)*10 + tt];
    else if (tt < 13) v = p.betas[(b2+eh)*3 + (tt-10)];
    else { int g = p.gender[b2+eh]; v = p.gender_tab[g*16 + (tt-13)]; }
    sf[X55f + eh*256 + tt] = v;          // condin
  }
  if (tt < 330) sf[BPFf + eh*330 + tt] = p.bp[(size_t)(b2+eh)*330 + tt];
  __syncthreads();
  // cond W1
  {
    float a = p.cond_b1[tt];
    #pragma unroll 1
    for (int k = 0; k < 29; ++k) a = fmaf(sf[X55f + eh*256 + k], p.cond_W1[k*512 + tt], a);
    sf[TMPFf + eh*512 + tt] = gelu_f(a);
  }
  __syncthreads();
  // cond W2 (2-way k-split per elem)
  {
    int c = tt & 255, pg = tt >> 8;
    float a = 0.f;
    for (int k = pg*256; k < pg*256 + 256; ++k)
      a = fmaf(sf[TMPFf + eh*512 + k], p.cond_W2[(size_t)k*256 + c], a);
    sf[PARTSGf + (eh*2 + pg)*256 + c] = a;
  }
  __syncthreads();
  if (t < 512){
    int e = t >> 8, c = t & 255;
    sf[CONDVf + e*256 + c] = p.cond_b2[c] + sf[PARTSGf + (e*2)*256 + c] + sf[PARTSGf + (e*2+1)*256 + c];
  }
  __syncthreads();
  if (wv == 0 || wv == 8){
    int e = wv >> 3;
    float v[4], s = 0.f, s2 = 0.f;
    #pragma unroll
    for (int u = 0; u < 4; ++u){ v[u] = sf[CONDVf + e*256 + lane + 64*u]; s += v[u]; s2 = fmaf(v[u], v[u], s2); }
    s = wred_sum(s); s2 = wred_sum(s2);
    float mean = s * (1.f/256.f);
    float var  = s2 * (1.f/256.f) - mean*mean;
    float rs = rsqrtf(var + 1e-5f);
    #pragma unroll
    for (int u = 0; u < 4; ++u){
      int n = lane + 64*u;
      sf[CONDVf + e*256 + n] = (v[u]-mean)*rs*p.cond_g[n] + p.cond_b[n];
    }
  }
  __syncthreads();
  // embed W1 -> h1 (arena)
  {
    int n = tt & 255, mb = tt >> 8;
    int h1o = ATTe + eh*14784;
    for (int m = mb; m < 55; m += 2){
      float a = p.pose_b1[n];
      #pragma unroll
      for (int k = 0; k < 6; ++k) a = fmaf(sf[BPFf + eh*330 + m*6 + k], p.pose_W1[k*256 + n], a);
      su[h1o + m*264 + n] = f2b(gelu_f(a));
    }
    if (t < 512) su[ATTe + (t>>8)*14784 + 55*264 + (t&255)] = 0;
  }
  __syncthreads();
  // embed GEMM + fixups -> xsr
  {
    f32x4 a0[4] = {fz,fz,fz,fz}, a1[4] = {fz,fz,fz,fz};
    gemm2(su, ATTe, ATTe + 14784, 264, p.wb + WP2, wv, 16, a0, a1, lane);
    #pragma unroll
    for (int e = 0; e < 2; ++e){
      f32x4* ac = e ? a1 : a0;
      #pragma unroll
      for (int m = 0; m < 4; ++m){
        #pragma unroll
        for (int j = 0; j < 4; ++j){
          int row = m*16 + hi*4 + j;
          float v = 0.f;
          if (row < 56){
            v = (row < 55) ? (ac[m][j] + p.pose_b2[col]) : p.transl_emb[col];
            v = p.mask_ids[(b2+e)*56 + row] ? v : p.mask_emb[col];
            v += p.joints[row*256 + col];
          }
          xsr[e][m][j] = v;
        }
      }
    }
  }
  __syncthreads();
  ln_regs(p.in_g, p.in_b, true);

  // ================= layers =================
  for (int l = 0; l < 4; ++l){
    const float* bqkv = p.sa_bqkv + l*768;

    for (int hp = 0; hp < 4; ++hp){
      // zero vT key-pads for both elems/heads
      {
        int e = t >> 9, hh2 = (t >> 8) & 1, d = (t >> 3) & 31, pd = t & 7;
        su[VTo + (e*2 + hh2)*2304 + d*72 + 56 + pd] = 0;
      }
      // QKV head-pair GEMM (N=192): waves 0..11
      if (wv < 12){
        f32x4 q0[4] = {fz,fz,fz,fz}, q1[4] = {fz,fz,fz,fz};
        gemm2(su, XB0/2, XB1/2, 264, p.wb + WQKV + (size_t)(l*4 + hp)*49152, wv, 12, q0, q1, lane);
        int c192 = wv*16 + (lane & 15);
        int part = c192 >> 6, hh2 = (c192 >> 5) & 1, d = c192 & 31;
        float bias = bqkv[part*256 + (hp*2 + hh2)*32 + d];
        if (part == 0) bias *= 0.17677669529663687f;
        #pragma unroll
        for (int e = 0; e < 2; ++e){
          f32x4* ac = e ? q1 : q0;
          #pragma unroll
          for (int m = 0; m < 4; ++m){
            #pragma unroll
            for (int j = 0; j < 4; ++j){
              int row = m*16 + hi*4 + j;
              if (row < 56){
                float v = ac[m][j] + bias;
                if (part == 0)      su[QPo + (e*2+hh2)*2240 + row*40 + d] = f2b(v);
                else if (part == 1) su[KPo + (e*2+hh2)*2240 + row*40 + d] = f2b(v);
                else                su[VTo + (e*2+hh2)*2304 + d*72 + row] = f2b(v);
              }
            }
          }
        }
      }
      __syncthreads();

      for (int hh = 0; hh < 2; ++hh){
        int e = wv >> 3, wq = wv & 7;
        // scores: 2 tiles per wave (m = wq>>1, n = (wq&1)*2 + i)
        {
          int m = wq >> 1;
          short8 a = *(const short8*)(su + QPo + (e*2+hh)*2240 + rcl(m*16 + (lane&15))*40 + (hi<<3));
          #pragma unroll
          for (int i = 0; i < 2; ++i){
            int n = (wq & 1)*2 + i;
            short8 bf_ = *(const short8*)(su + KPo + (e*2+hh)*2240 + rcl(n*16 + (lane&15))*40 + (hi<<3));
            f32x4 d = MFMA16(a, bf_, fz);
            #pragma unroll
            for (int j = 0; j < 4; ++j){
              int row = m*16 + hi*4 + j, key = n*16 + (lane & 15);
              if (row < 56 && key < 56)
                su[SCBo + e*SCST + row*72 + key] = f2b(d[j] + p.rel_map[row*56 + key]);
            }
          }
        }
        __syncthreads();
        // softmax: 7 rows per wave
        #pragma unroll
        for (int q = 0; q < 7; ++q){
          int r = wq*7 + q;
          float v = (lane < 56) ? b2f(su[SCBo + e*SCST + r*72 + lane]) : -3.0e38f;
          float mx = wred_max(v);
          float ex = (lane < 56) ? __expf(v - mx) : 0.f;
          float s = wred_sum(ex);
          float a = ex / s;
          su[SCBo + e*SCST + r*72 + lane] = (lane < 56) ? f2b(a) : (unsigned short)0;
          if (l == 3) awr[q] += a * 0.125f;
        }
        __syncthreads();
        // PV: 1 tile per wave (m = wq>>1, dt = wq&1)
        {
          int m = wq >> 1, dt = wq & 1;
          f32x4 o = fz;
          #pragma unroll
          for (int ks = 0; ks < 2; ++ks){
            short8 a  = *(const short8*)(su + SCBo + e*SCST + rcl(m*16 + (lane&15))*72 + ks*32 + (hi<<3));
            short8 bf_= *(const short8*)(su + VTo + (e*2+hh)*2304 + (dt*16 + (lane&15))*72 + ks*32 + (hi<<3));
            o = MFMA16(a, bf_, o);
          }
          #pragma unroll
          for (int j = 0; j < 4; ++j){
            int row = m*16 + hi*4 + j;
            if (row < 56) su[OHo + e*2240 + row*40 + dt*16 + (lane & 15)] = f2b(o[j]);
          }
        }
        __syncthreads();
        // AO (K=32) accumulate into xsr
        {
          short8 bo = *(const short8*)(p.wb + WO + (size_t)(((l*8 + hp*2 + hh)*16) + wv)*512 + lane*8);
          #pragma unroll
          for (int e2 = 0; e2 < 2; ++e2){
            #pragma unroll
            for (int m = 0; m < 4; ++m){
              short8 a = *(const short8*)(su + OHo + e2*2240 + rcl(m*16 + (lane&15))*40 + (hi<<3));
              xsr[e2][m] = MFMA16(a, bo, xsr[e2][m]);
            }
          }
        }
        __syncthreads();
      }
    } // head pairs

    // AO bias + LN1
    {
      float bo = p.sa_bo[l*256 + col];
      #pragma unroll
      for (int e = 0; e < 2; ++e)
        #pragma unroll
        for (int m = 0; m < 4; ++m)
          #pragma unroll
          for (int j = 0; j < 4; ++j) xsr[e][m][j] += bo;
    }
    ln_regs(p.ln1_g + l*256, p.ln1_b + l*256, false);

    // collapsed cross-attn (2 GEMVs, 2-way k-split per elem)
    __syncthreads();  // protect PARTSG (overlaps stats users done above)
    {
      int c = tt & 255, pg = tt >> 8;
      float a = 0.f;
      const float* W = p.ca_Wkv + (size_t)l*131072 + 256 + c;
      for (int k = pg*128; k < pg*128 + 128; ++k) a = fmaf(sf[CONDVf + eh*256 + k], W[(size_t)k*512], a);
      sf[PARTSGf + (eh*2 + pg)*256 + c] = a;
    }
    __syncthreads();
    if (t < 512){
      int e = t >> 8, c = t & 255;
      sf[VCSBf + e*256 + c] = p.ca_bkv[l*512 + 256 + c] + sf[PARTSGf + e*2*256 + c] + sf[PARTSGf + (e*2+1)*256 + c];
    }
    __syncthreads();
    {
      int c = tt & 255, pg = tt >> 8;
      float a = 0.f;
      const float* W = p.ca_Wo + (size_t)l*65536 + c;
      for (int k = pg*128; k < pg*128 + 128; ++k) a = fmaf(sf[VCSBf + eh*256 + k], W[(size_t)k*256], a);
      sf[PARTSGf + (eh*2 + pg)*256 + c] = a;
    }
    __syncthreads();
    if (t < 512){
      int e = t >> 8, c = t & 255;
      sf[OCVf + e*256 + c] = p.ca_bo[l*256 + c] + sf[PARTSGf + e*2*256 + c] + sf[PARTSGf + (e*2+1)*256 + c];
    }
    __syncthreads();
    {
      float o0 = sf[OCVf + col], o1 = sf[OCVf + 256 + col];
      #pragma unroll
      for (int m = 0; m < 4; ++m)
        #pragma unroll
        for (int j = 0; j < 4; ++j){ xsr[0][m][j] += o0; xsr[1][m][j] += o1; }
    }
    __syncthreads();  // OCV reads done before LN partials overwrite region
    ln_regs(p.ln2_g + l*256, p.ln2_b + l*256, true);

    // FF
    for (int ch = 0; ch < 4; ++ch){
      f32x4 f0[4] = {fz,fz,fz,fz}, f1[4] = {fz,fz,fz,fz};
      gemm2(su, XB0/2, XB1/2, 264, p.wb + WF1 + (size_t)(l*4 + ch)*65536, wv, 16, f0, f1, lane);
      const float* b1 = p.ff_b1 + l*1024 + ch*256;
      #pragma unroll
      for (int e = 0; e < 2; ++e){
        f32x4* fc = e ? f1 : f0;
        int h1o = ATTe + e*14784;
        #pragma unroll
        for (int m = 0; m < 4; ++m){
          #pragma unroll
          for (int j = 0; j < 4; ++j){
            int row = m*16 + hi*4 + j;
            if (row < 56) su[h1o + row*264 + col] = f2b(gelu_f(fc[m][j] + b1[col]));
          }
        }
      }
      __syncthreads();
      gemm2(su, ATTe, ATTe + 14784, 264, p.wb + WF2 + (size_t)(l*4 + ch)*65536, wv, 16, xsr[0], xsr[1], lane);
      __syncthreads();
    }
    {
      float bo = p.ff_b2[l*256 + col];
      #pragma unroll
      for (int e = 0; e < 2; ++e)
        #pragma unroll
        for (int m = 0; m < 4; ++m)
          #pragma unroll
          for (int j = 0; j < 4; ++j) xsr[e][m][j] += bo;
    }
    ln_regs(p.ln3_g + l*256, p.ln3_b + l*256, true);
  } // layers

  // ---- attn_w out ----
  {
    int e = wv >> 3, wq = wv & 7;
    if (lane < 56){
      #pragma unroll
      for (int q = 0; q < 7; ++q)
        p.out[OUT_AW + (size_t)(b2+e)*3136 + (wq*7 + q)*56 + lane] = awr[q];
    }
  }
  // ---- x row 55 -> LDS for transl ----
  if (hi == 1){
    sf[X55f + 0*256 + col] = xsr[0][3][3];
    sf[X55f + 1*256 + col] = xsr[1][3][3];
  }

  // ---- pose head ----
  {
    float pacc = 0.f;
    int mp = tt / 6, op = tt - mp*6;
    for (int ch = 0; ch < 4; ++ch){
      f32x4 r0[4] = {fz,fz,fz,fz}, r1[4] = {fz,fz,fz,fz};
      gemm2(su, XB0/2, XB1/2, 264, p.wb + WROT + (size_t)ch*65536, wv, 16, r0, r1, lane);
      const float* rb = p.rot_b1 + ch*256;
      #pragma unroll
      for (int e = 0; e < 2; ++e){
        f32x4* rc = e ? r1 : r0;
        int h1o = ATTe + e*14784;
        #pragma unroll
        for (int m = 0; m < 4; ++m){
          #pragma unroll
          for (int j = 0; j < 4; ++j){
            int row = m*16 + hi*4 + j;
            if (row < 56) su[h1o + row*264 + col] = f2b(gelu_f(rc[m][j] + rb[col]));
          }
        }
      }
      __syncthreads();
      if (tt < 330){
        int h1o = ATTe + eh*14784;
        for (int d = 0; d < 256; ++d)
          pacc = fmaf(b2f(su[h1o + mp*264 + d]), p.rot_W2[(size_t)(ch*256 + d)*6 + op], pacc);
      }
      __syncthreads();
    }
    if (tt < 330) p.out[(size_t)(b2+eh)*330 + tt] = pacc + p.rot_b2[op];
  }

  // ---- transl head ----
  {
    #pragma unroll
    for (int hf = 0; hf < 2; ++hf){
      int c = tt + hf*512;
      float a = p.tr_b1[c];
      for (int k = 0; k < 256; ++k) a = fmaf(sf[X55f + eh*256 + k], p.tr_W1[(size_t)k*1024 + c], a);
      sf[TRFf + eh*1024 + c] = gelu_f(a);
    }
    __syncthreads();
    float part = 0.f;
    #pragma unroll
    for (int hf = 0; hf < 2; ++hf){
      int c = tt + hf*512;
      part = fmaf(sf[TRFf + eh*1024 + c], p.tr_W2[c], part);
    }
    part = wred_sum(part);
    if (lane == 0) sf[WSUMf + wv] = part;
    __syncthreads();
    if (t == 0){
      float s = p.tr_b2[0];
      #pragma unroll
      for (int w = 0; w < 8; ++w) s += sf[WSUMf + w];
      p.out[OUT_TR + b2] = s;
    }
    if (t == 512){
      float s = p.tr_b2[0];
      #pragma unroll
      for (int w = 8; w < 16; ++w) s += sf[WSUMf + w];
      p.out[OUT_TR + b2 + 1] = s;
    }
  }
}

extern "C" void kernel_launch(void* const* d_in, const int* in_sizes, int n_in,
                              void* d_out, int out_size, void* d_ws, size_t ws_size,
                              hipStream_t stream){
  (void)in_sizes; (void)n_in; (void)out_size; (void)ws_size;
  auto F = [&](int i) -> const float* { return (const float*)d_in[i]; };

  PP pp;
  pp.sa_Wqkv = F(20); pp.sa_Wo = F(22); pp.ff_W1 = F(30); pp.ff_W2 = F(32);
  pp.rot_W1 = F(40); pp.pose_W2 = F(5);
  pp.wb = (unsigned short*)d_ws;
  hipLaunchKernelGGL(prep_kernel, dim3((WTOT + 255u)/256u), dim3(256), 0, stream, pp);

  KP p;
  p.bp = F(0); p.wrist = F(1); p.betas = F(2);
  p.pose_W1 = F(3); p.pose_b1 = F(4); p.pose_b2 = F(6);
  p.joints = F(7); p.mask_emb = F(8); p.transl_emb = F(9);
  p.in_g = F(10); p.in_b = F(11);
  p.gender_tab = F(12);
  p.cond_W1 = F(13); p.cond_b1 = F(14); p.cond_W2 = F(15); p.cond_b2 = F(16);
  p.cond_g = F(17); p.cond_b = F(18);
  p.rel_map = F(19);
  p.sa_bqkv = F(21); p.sa_bo = F(23);
  p.ca_Wkv = F(26); p.ca_bkv = F(27); p.ca_Wo = F(28); p.ca_bo = F(29);
  p.ff_b1 = F(31); p.ff_b2 = F(33);
  p.ln1_g = F(34); p.ln1_b = F(35); p.ln2_g = F(36); p.ln2_b = F(37);
  p.ln3_g = F(38); p.ln3_b = F(39);
  p.rot_b1 = F(41); p.rot_W2 = F(42); p.rot_b2 = F(43);
  p.tr_W1 = F(44); p.tr_b1 = F(45); p.tr_W2 = F(46); p.tr_b2 = F(47);
  p.gender = (const int*)d_in[48]; p.mask_ids = (const int*)d_in[49];
  p.wb = (const unsigned short*)d_ws;
  p.out = (float*)d_out;

  hipLaunchKernelGGL(actor_kernel, dim3(NB), dim3(Tc), 0, stream, p);
}

// Round 9
// 6357.192 us; speedup vs baseline: 3.6795x; 1.0703x over previous
//
#include <hip/hip_runtime.h>
#include <hip/hip_bf16.h>

#define DEV static __device__ __forceinline__

typedef __attribute__((ext_vector_type(8))) short short8;
typedef __attribute__((ext_vector_type(4))) float f32x4;
#define MFMA16(a,b,c) __builtin_amdgcn_mfma_f32_16x16x32_bf16(a,b,c,0,0,0)

constexpr int Tc = 1024;
constexpr int NB = 1024;              // blocks; 2 batch elems each
constexpr int OUT_TR = 675840;
constexpr int OUT_AW = 677888;

// ---- d_ws bf16 frag-linear (u16 offsets) ----
constexpr unsigned WQKV = 0;          // l4 x hp4 x ks8 x ct12 x 512 (q-scale folded)
constexpr unsigned WO   = 786432;     // l4 x h8 x ct16 x 512   (K=32 per head)
constexpr unsigned WF1  = 1048576;    // l4 x ch4 x ks8 x ct16 x 512
constexpr unsigned WF2  = 2097152;    // l4 x ch4(k) x ks8 x ct16 x 512
constexpr unsigned WROT = 3145728;    // ch4 x ks8 x ct16 x 512
constexpr unsigned WP2  = 3407872;    // ks8 x ct16 x 512
constexpr unsigned WTOT = 3473408;

// ---- LDS (bytes) ----
constexpr int XB0 = 0;                // u16 [56][264]
constexpr int XB1 = 29568;
constexpr int ATT = 59136;            // 79360-byte arena
constexpr int STATS = 138496;         // f32 [2][128] (mean|rstd)
constexpr int CONDV = 140544;         // f32 [2][256]
constexpr int X55  = 142592;          // f32 [2][256] (also condin)
constexpr int SMEM_TOT = 144640;

// u16 offsets in arena
constexpr int ATTe = ATT/2;
constexpr int QPo  = ATTe;            // (e*2+hh)*2240 + row*40 + d
constexpr int KPo  = ATTe + 8960;
constexpr int VTo  = ATTe + 17920;    // (e*2+hh)*2304 + d*72 + row
constexpr int SCBo = ATTe + 27136;    // e*4032 + row*72 + key
constexpr int SCST = 4032;
constexpr int OHo  = ATTe + 35200;    // e*2240 + row*40 + d  (= SCBo + 2*4032, packs exactly)
// f32 indices (into (float*)smem)
constexpr int PARTS_S  = 14784;       // [2][16][64]
constexpr int PARTS_S2 = 16832;
constexpr int PARTSGf  = 14784;       // GEMV partials [2][2][256]
constexpr int VCSBf    = 15808;
constexpr int OCVf     = 16320;
constexpr int TMPFf    = 16832;       // cond hidden [2][512]
constexpr int BPFf     = 29568;       // body_pose stage [2][330]
constexpr int TRFf     = 14784;       // transl hidden [2][1024]
constexpr int STATSf   = 34624;
constexpr int WSUMf    = 34624;
constexpr int CONDVf   = 35136;
constexpr int X55f     = 35648;

struct PP {
  const float *sa_Wqkv,*sa_Wo,*ff_W1,*ff_W2,*rot_W1,*pose_W2;
  unsigned short* wb;
};
struct KP {
  const float *bp,*wrist,*betas;
  const float *pose_W1,*pose_b1,*pose_b2;
  const float *joints,*mask_emb,*transl_emb,*in_g,*in_b;
  const float *gender_tab,*cond_W1,*cond_b1,*cond_W2,*cond_b2,*cond_g,*cond_b;
  const float *rel_map;
  const float *sa_bqkv,*sa_bo;
  const float *ca_Wkv,*ca_bkv,*ca_Wo,*ca_bo;
  const float *ff_b1,*ff_b2;
  const float *ln1_g,*ln1_b,*ln2_g,*ln2_b,*ln3_g,*ln3_b;
  const float *rot_b1,*rot_W2,*rot_b2;
  const float *tr_W1,*tr_b1,*tr_W2,*tr_b2;
  const int *gender,*mask_ids;
  const unsigned short* wb;
  float* out;
};

DEV unsigned short f2b(float x){
  union { __hip_bfloat16 h; unsigned short u; } c; c.h = __float2bfloat16(x); return c.u;
}
DEV float b2f(unsigned short u){
  union { __hip_bfloat16 h; unsigned short u; } c; c.u = u; return __bfloat162float(c.h);
}
DEV float gelu_f(float x){
  float z = 0.7978845608028654f * (x + 0.044715f * x * x * x);
  return x / (1.0f + __expf(-2.0f * z));
}
DEV float wred_sum(float v){
  #pragma unroll
  for (int m = 32; m; m >>= 1) v += __shfl_xor(v, m, 64);
  return v;
}
DEV float wred_max(float v){
  #pragma unroll
  for (int m = 32; m; m >>= 1) v = fmaxf(v, __shfl_xor(v, m, 64));
  return v;
}
DEV int rcl(int r){ return r > 55 ? 55 : r; }

// ================= prep =================
__global__ __launch_bounds__(256)
void prep_kernel(PP a){
  unsigned i = blockIdx.x*256u + threadIdx.x;
  if (i >= WTOT) return;
  float v;
  if (i < WO){                                   // WQKV
    unsigned l=i/196608u, r=i%196608u, hp=r/49152u, r2=r%49152u;
    unsigned ks=r2/6144u, r3=r2%6144u, ct=r3/512u, r4=r3&511u;
    unsigned lane=r4>>3, e=r4&7u;
    unsigned c192=ct*16u+(lane&15u), k=ks*32u+((lane>>4)<<3)+e;
    unsigned part=c192>>6, hh=(c192>>5)&1u, d=c192&31u;
    v = a.sa_Wqkv[l*196608u + k*768u + part*256u + (hp*2u+hh)*32u + d];
    if (part==0u) v *= 0.17677669529663687f;
  } else if (i < WF1){                           // WO per-head K=32
    unsigned j=i-WO, l=j/65536u, r=j%65536u, h=r/8192u, r2=r%8192u;
    unsigned ct=r2/512u, r4=r2&511u, lane=r4>>3, e=r4&7u;
    unsigned col=ct*16u+(lane&15u), k=((lane>>4)<<3)+e;
    v = a.sa_Wo[l*65536u + (h*32u+k)*256u + col];
  } else if (i < WF2){                           // WF1
    unsigned j=i-WF1, l=j/262144u, r=j%262144u, ch=r/65536u, r2=r%65536u;
    unsigned ks=r2/8192u, r3=r2%8192u, ct=r3/512u, r4=r3&511u, lane=r4>>3, e=r4&7u;
    unsigned col=ct*16u+(lane&15u), k=ks*32u+((lane>>4)<<3)+e;
    v = a.ff_W1[l*262144u + k*1024u + ch*256u + col];
  } else if (i < WROT){                          // WF2
    unsigned j=i-WF2, l=j/262144u, r=j%262144u, ch=r/65536u, r2=r%65536u;
    unsigned ks=r2/8192u, r3=r2%8192u, ct=r3/512u, r4=r3&511u, lane=r4>>3, e=r4&7u;
    unsigned col=ct*16u+(lane&15u), k=ks*32u+((lane>>4)<<3)+e;
    v = a.ff_W2[l*262144u + (ch*256u+k)*256u + col];
  } else if (i < WP2){                           // WROT
    unsigned j=i-WROT, ch=j/65536u, r2=j%65536u;
    unsigned ks=r2/8192u, r3=r2%8192u, ct=r3/512u, r4=r3&511u, lane=r4>>3, e=r4&7u;
    unsigned col=ct*16u+(lane&15u), k=ks*32u+((lane>>4)<<3)+e;
    v = a.rot_W1[k*1024u + ch*256u + col];
  } else {                                       // WP2
    unsigned j=i-WP2, ks=j/8192u, r3=j%8192u;
    unsigned ct=r3/512u, r4=r3&511u, lane=r4>>3, e=r4&7u;
    unsigned col=ct*16u+(lane&15u), k=ks*32u+((lane>>4)<<3)+e;
    v = a.pose_W2[k*256u + col];
  }
  a.wb[i] = f2b(v);
}

// ================= helpers =================
// E=2 GEMM: B frag-linear from global (shared), A0/A1 bf16 LDS (stride astr)
DEV void gemm2(const unsigned short* su, int a0o, int a1o, int astr,
               const unsigned short* Bg, int ct, int nct,
               f32x4* C0, f32x4* C1, int lane){
  int ro[4];
  #pragma unroll
  for (int m = 0; m < 4; ++m) ro[m] = rcl(m*16 + (lane & 15))*astr + ((lane >> 4) << 3);
  short8 b[8];
  #pragma unroll
  for (int ks = 0; ks < 8; ++ks)
    b[ks] = *(const short8*)(Bg + (size_t)(ks*nct + ct)*512 + lane*8);
  #pragma unroll
  for (int ks = 0; ks < 8; ++ks){
    #pragma unroll
    for (int m = 0; m < 4; ++m){
      short8 a0 = *(const short8*)(su + a0o + ro[m] + ks*32);
      C0[m] = MFMA16(a0, b[ks], C0[m]);
      short8 a1 = *(const short8*)(su + a1o + ro[m] + ks*32);
      C1[m] = MFMA16(a1, b[ks], C1[m]);
    }
  }
}

__global__ __launch_bounds__(Tc) __attribute__((amdgpu_waves_per_eu(4, 4)))
void actor_kernel(KP p){
  __shared__ __align__(16) char smem[SMEM_TOT];
  float* sf = (float*)smem;
  unsigned short* su = (unsigned short*)smem;

  const int t = threadIdx.x;
  const int lane = t & 63, wv = t >> 6;
  const int hi = lane >> 4;
  const int col = wv*16 + (lane & 15);
  const int b2 = blockIdx.x * 2;
  const int eh = t >> 9, tt = t & 511;   // elem-half split
  const f32x4 fz = {0.f,0.f,0.f,0.f};

  f32x4 xsr[2][4];                       // x fp32 resident in regs (16-col slice)
  float awr[7] = {0,0,0,0,0,0,0};

  // ---- LN over reg-x: 2(+1 if wxb) barriers ----
  auto ln_regs = [&](const float* g, const float* bta, bool wxb){
    #pragma unroll
    for (int e = 0; e < 2; ++e){
      #pragma unroll
      for (int m = 0; m < 4; ++m){
        #pragma unroll
        for (int j = 0; j < 4; ++j){
          float s = xsr[e][m][j], s2 = s*s;
          #pragma unroll
          for (int mk = 1; mk < 16; mk <<= 1){
            s += __shfl_xor(s, mk, 64); s2 += __shfl_xor(s2, mk, 64);
          }
          if ((lane & 15) == 0){
            int row = m*16 + hi*4 + j;
            sf[PARTS_S  + (e*16 + wv)*64 + row] = s;
            sf[PARTS_S2 + (e*16 + wv)*64 + row] = s2;
          }
        }
      }
    }
    __syncthreads();
    if (t < 128){
      int e = t >> 6, row = t & 63;
      float s = 0.f, s2 = 0.f;
      #pragma unroll
      for (int w = 0; w < 16; ++w){
        s  += sf[PARTS_S  + (e*16 + w)*64 + row];
        s2 += sf[PARTS_S2 + (e*16 + w)*64 + row];
      }
      float mean = s * (1.f/256.f);
      float var  = s2 * (1.f/256.f) - mean*mean;
      sf[STATSf + e*128 + row]      = mean;
      sf[STATSf + e*128 + 64 + row] = rsqrtf(var + 1e-5f);
    }
    __syncthreads();
    float gg = g[col], bb = bta[col];
    #pragma unroll
    for (int e = 0; e < 2; ++e){
      int xbo = (e ? XB1 : XB0) / 2;
      #pragma unroll
      for (int m = 0; m < 4; ++m){
        #pragma unroll
        for (int j = 0; j < 4; ++j){
          int row = m*16 + hi*4 + j;
          float mean = sf[STATSf + e*128 + row];
          float rstd = sf[STATSf + e*128 + 64 + row];
          float o = (xsr[e][m][j] - mean) * rstd * gg + bb;
          xsr[e][m][j] = o;
          if (wxb && row < 56) su[xbo + row*264 + col] = f2b(o);
        }
      }
    }
    if (wxb) __syncthreads();
  };

  // ================= prologue =================
  if (tt < 29){
    float v;
    if (tt < 10) v = p.wrist[(b2+eh)*10 + tt];
    else if (tt < 13) v = p.betas[(b2+eh)*3 + (tt-10)];
    else { int g = p.gender[b2+eh]; v = p.gender_tab[g*16 + (tt-13)]; }
    sf[X55f + eh*256 + tt] = v;          // condin
  }
  if (tt < 330) sf[BPFf + eh*330 + tt] = p.bp[(size_t)(b2+eh)*330 + tt];
  __syncthreads();
  // cond W1
  {
    float a = p.cond_b1[tt];
    #pragma unroll 1
    for (int k = 0; k < 29; ++k) a = fmaf(sf[X55f + eh*256 + k], p.cond_W1[k*512 + tt], a);
    sf[TMPFf + eh*512 + tt] = gelu_f(a);
  }
  __syncthreads();
  // cond W2 (2-way k-split per elem)
  {
    int c = tt & 255, pg = tt >> 8;
    float a = 0.f;
    for (int k = pg*256; k < pg*256 + 256; ++k)
      a = fmaf(sf[TMPFf + eh*512 + k], p.cond_W2[(size_t)k*256 + c], a);
    sf[PARTSGf + (eh*2 + pg)*256 + c] = a;
  }
  __syncthreads();
  if (t < 512){
    int e = t >> 8, c = t & 255;
    sf[CONDVf + e*256 + c] = p.cond_b2[c] + sf[PARTSGf + (e*2)*256 + c] + sf[PARTSGf + (e*2+1)*256 + c];
  }
  __syncthreads();
  if (wv == 0 || wv == 8){
    int e = wv >> 3;
    float v[4], s = 0.f, s2 = 0.f;
    #pragma unroll
    for (int u = 0; u < 4; ++u){ v[u] = sf[CONDVf + e*256 + lane + 64*u]; s += v[u]; s2 = fmaf(v[u], v[u], s2); }
    s = wred_sum(s); s2 = wred_sum(s2);
    float mean = s * (1.f/256.f);
    float var  = s2 * (1.f/256.f) - mean*mean;
    float rs = rsqrtf(var + 1e-5f);
    #pragma unroll
    for (int u = 0; u < 4; ++u){
      int n = lane + 64*u;
      sf[CONDVf + e*256 + n] = (v[u]-mean)*rs*p.cond_g[n] + p.cond_b[n];
    }
  }
  __syncthreads();
  // embed W1 -> h1 (arena)
  {
    int n = tt & 255, mb = tt >> 8;
    int h1o = ATTe + eh*14784;
    for (int m = mb; m < 55; m += 2){
      float a = p.pose_b1[n];
      #pragma unroll
      for (int k = 0; k < 6; ++k) a = fmaf(sf[BPFf + eh*330 + m*6 + k], p.pose_W1[k*256 + n], a);
      su[h1o + m*264 + n] = f2b(gelu_f(a));
    }
    if (t < 512) su[ATTe + (t>>8)*14784 + 55*264 + (t&255)] = 0;
  }
  __syncthreads();
  // embed GEMM + fixups -> xsr
  {
    f32x4 a0[4] = {fz,fz,fz,fz}, a1[4] = {fz,fz,fz,fz};
    gemm2(su, ATTe, ATTe + 14784, 264, p.wb + WP2, wv, 16, a0, a1, lane);
    #pragma unroll
    for (int e = 0; e < 2; ++e){
      f32x4* ac = e ? a1 : a0;
      #pragma unroll
      for (int m = 0; m < 4; ++m){
        #pragma unroll
        for (int j = 0; j < 4; ++j){
          int row = m*16 + hi*4 + j;
          float v = 0.f;
          if (row < 56){
            v = (row < 55) ? (ac[m][j] + p.pose_b2[col]) : p.transl_emb[col];
            v = p.mask_ids[(b2+e)*56 + row] ? v : p.mask_emb[col];
            v += p.joints[row*256 + col];
          }
          xsr[e][m][j] = v;
        }
      }
    }
  }
  __syncthreads();
  ln_regs(p.in_g, p.in_b, true);

  // ================= layers =================
  for (int l = 0; l < 4; ++l){
    const float* bqkv = p.sa_bqkv + l*768;

    for (int hp = 0; hp < 4; ++hp){
      // zero vT key-pads for both elems/heads
      {
        int e = t >> 9, hh2 = (t >> 8) & 1, d = (t >> 3) & 31, pd = t & 7;
        su[VTo + (e*2 + hh2)*2304 + d*72 + 56 + pd] = 0;
      }
      // QKV head-pair GEMM (N=192): waves 0..11
      if (wv < 12){
        f32x4 q0[4] = {fz,fz,fz,fz}, q1[4] = {fz,fz,fz,fz};
        gemm2(su, XB0/2, XB1/2, 264, p.wb + WQKV + (size_t)(l*4 + hp)*49152, wv, 12, q0, q1, lane);
        int c192 = wv*16 + (lane & 15);
        int part = c192 >> 6, hh2 = (c192 >> 5) & 1, d = c192 & 31;
        float bias = bqkv[part*256 + (hp*2 + hh2)*32 + d];
        if (part == 0) bias *= 0.17677669529663687f;
        #pragma unroll
        for (int e = 0; e < 2; ++e){
          f32x4* ac = e ? q1 : q0;
          #pragma unroll
          for (int m = 0; m < 4; ++m){
            #pragma unroll
            for (int j = 0; j < 4; ++j){
              int row = m*16 + hi*4 + j;
              if (row < 56){
                float v = ac[m][j] + bias;
                if (part == 0)      su[QPo + (e*2+hh2)*2240 + row*40 + d] = f2b(v);
                else if (part == 1) su[KPo + (e*2+hh2)*2240 + row*40 + d] = f2b(v);
                else                su[VTo + (e*2+hh2)*2304 + d*72 + row] = f2b(v);
              }
            }
          }
        }
      }
      __syncthreads();

      for (int hh = 0; hh < 2; ++hh){
        int e = wv >> 3, wq = wv & 7;
        // scores: 2 tiles per wave (m = wq>>1, n = (wq&1)*2 + i)
        {
          int m = wq >> 1;
          short8 a = *(const short8*)(su + QPo + (e*2+hh)*2240 + rcl(m*16 + (lane&15))*40 + (hi<<3));
          #pragma unroll
          for (int i = 0; i < 2; ++i){
            int n = (wq & 1)*2 + i;
            short8 bf_ = *(const short8*)(su + KPo + (e*2+hh)*2240 + rcl(n*16 + (lane&15))*40 + (hi<<3));
            f32x4 d = MFMA16(a, bf_, fz);
            #pragma unroll
            for (int j = 0; j < 4; ++j){
              int row = m*16 + hi*4 + j, key = n*16 + (lane & 15);
              if (row < 56 && key < 56)
                su[SCBo + e*SCST + row*72 + key] = f2b(d[j] + p.rel_map[row*56 + key]);
            }
          }
        }
        __syncthreads();
        // softmax: 7 rows per wave
        #pragma unroll
        for (int q = 0; q < 7; ++q){
          int r = wq*7 + q;
          float v = (lane < 56) ? b2f(su[SCBo + e*SCST + r*72 + lane]) : -3.0e38f;
          float mx = wred_max(v);
          float ex = (lane < 56) ? __expf(v - mx) : 0.f;
          float s = wred_sum(ex);
          float a = ex / s;
          su[SCBo + e*SCST + r*72 + lane] = (lane < 56) ? f2b(a) : (unsigned short)0;
          if (l == 3) awr[q] += a * 0.125f;
        }
        __syncthreads();
        // PV: 1 tile per wave (m = wq>>1, dt = wq&1)
        {
          int m = wq >> 1, dt = wq & 1;
          f32x4 o = fz;
          #pragma unroll
          for (int ks = 0; ks < 2; ++ks){
            short8 a  = *(const short8*)(su + SCBo + e*SCST + rcl(m*16 + (lane&15))*72 + ks*32 + (hi<<3));
            short8 bf_= *(const short8*)(su + VTo + (e*2+hh)*2304 + (dt*16 + (lane&15))*72 + ks*32 + (hi<<3));
            o = MFMA16(a, bf_, o);
          }
          #pragma unroll
          for (int j = 0; j < 4; ++j){
            int row = m*16 + hi*4 + j;
            if (row < 56) su[OHo + e*2240 + row*40 + dt*16 + (lane & 15)] = f2b(o[j]);
          }
        }
        __syncthreads();
        // AO (K=32) accumulate into xsr
        {
          short8 bo = *(const short8*)(p.wb + WO + (size_t)(((l*8 + hp*2 + hh)*16) + wv)*512 + lane*8);
          #pragma unroll
          for (int e2 = 0; e2 < 2; ++e2){
            #pragma unroll
            for (int m = 0; m < 4; ++m){
              short8 a = *(const short8*)(su + OHo + e2*2240 + rcl(m*16 + (lane&15))*40 + (hi<<3));
              xsr[e2][m] = MFMA16(a, bo, xsr[e2][m]);
            }
          }
        }
        __syncthreads();
      }
    } // head pairs

    // AO bias + LN1
    {
      float bo = p.sa_bo[l*256 + col];
      #pragma unroll
      for (int e = 0; e < 2; ++e)
        #pragma unroll
        for (int m = 0; m < 4; ++m)
          #pragma unroll
          for (int j = 0; j < 4; ++j) xsr[e][m][j] += bo;
    }
    ln_regs(p.ln1_g + l*256, p.ln1_b + l*256, false);

    // collapsed cross-attn (2 GEMVs, 2-way k-split per elem)
    __syncthreads();  // protect PARTSG (overlaps stats users done above)
    {
      int c = tt & 255, pg = tt >> 8;
      float a = 0.f;
      const float* W = p.ca_Wkv + (size_t)l*131072 + 256 + c;
      for (int k = pg*128; k < pg*128 + 128; ++k) a = fmaf(sf[CONDVf + eh*256 + k], W[(size_t)k*512], a);
      sf[PARTSGf + (eh*2 + pg)*256 + c] = a;
    }
    __syncthreads();
    if (t < 512){
      int e = t >> 8, c = t & 255;
      sf[VCSBf + e*256 + c] = p.ca_bkv[l*512 + 256 + c] + sf[PARTSGf + e*2*256 + c] + sf[PARTSGf + (e*2+1)*256 + c];
    }
    __syncthreads();
    {
      int c = tt & 255, pg = tt >> 8;
      float a = 0.f;
      const float* W = p.ca_Wo + (size_t)l*65536 + c;
      for (int k = pg*128; k < pg*128 + 128; ++k) a = fmaf(sf[VCSBf + eh*256 + k], W[(size_t)k*256], a);
      sf[PARTSGf + (eh*2 + pg)*256 + c] = a;
    }
    __syncthreads();
    if (t < 512){
      int e = t >> 8, c = t & 255;
      sf[OCVf + e*256 + c] = p.ca_bo[l*256 + c] + sf[PARTSGf + e*2*256 + c] + sf[PARTSGf + (e*2+1)*256 + c];
    }
    __syncthreads();
    {
      float o0 = sf[OCVf + col], o1 = sf[OCVf + 256 + col];
      #pragma unroll
      for (int m = 0; m < 4; ++m)
        #pragma unroll
        for (int j = 0; j < 4; ++j){ xsr[0][m][j] += o0; xsr[1][m][j] += o1; }
    }
    __syncthreads();  // OCV reads done before LN partials overwrite region
    ln_regs(p.ln2_g + l*256, p.ln2_b + l*256, true);

    // FF
    for (int ch = 0; ch < 4; ++ch){
      f32x4 f0[4] = {fz,fz,fz,fz}, f1[4] = {fz,fz,fz,fz};
      gemm2(su, XB0/2, XB1/2, 264, p.wb + WF1 + (size_t)(l*4 + ch)*65536, wv, 16, f0, f1, lane);
      const float* b1 = p.ff_b1 + l*1024 + ch*256;
      #pragma unroll
      for (int e = 0; e < 2; ++e){
        f32x4* fc = e ? f1 : f0;
        int h1o = ATTe + e*14784;
        #pragma unroll
        for (int m = 0; m < 4; ++m){
          #pragma unroll
          for (int j = 0; j < 4; ++j){
            int row = m*16 + hi*4 + j;
            if (row < 56) su[h1o + row*264 + col] = f2b(gelu_f(fc[m][j] + b1[col]));
          }
        }
      }
      __syncthreads();
      gemm2(su, ATTe, ATTe + 14784, 264, p.wb + WF2 + (size_t)(l*4 + ch)*65536, wv, 16, xsr[0], xsr[1], lane);
      __syncthreads();
    }
    {
      float bo = p.ff_b2[l*256 + col];
      #pragma unroll
      for (int e = 0; e < 2; ++e)
        #pragma unroll
        for (int m = 0; m < 4; ++m)
          #pragma unroll
          for (int j = 0; j < 4; ++j) xsr[e][m][j] += bo;
    }
    ln_regs(p.ln3_g + l*256, p.ln3_b + l*256, true);
  } // layers

  // ---- attn_w out ----
  {
    int e = wv >> 3, wq = wv & 7;
    if (lane < 56){
      #pragma unroll
      for (int q = 0; q < 7; ++q)
        p.out[OUT_AW + (size_t)(b2+e)*3136 + (wq*7 + q)*56 + lane] = awr[q];
    }
  }
  // ---- x row 55 -> LDS for transl ----
  if (hi == 1){
    sf[X55f + 0*256 + col] = xsr[0][3][3];
    sf[X55f + 1*256 + col] = xsr[1][3][3];
  }

  // ---- pose head ----
  {
    float pacc = 0.f;
    int mp = tt / 6, op = tt - mp*6;
    for (int ch = 0; ch < 4; ++ch){
      f32x4 r0[4] = {fz,fz,fz,fz}, r1[4] = {fz,fz,fz,fz};
      gemm2(su, XB0/2, XB1/2, 264, p.wb + WROT + (size_t)ch*65536, wv, 16, r0, r1, lane);
      const float* rb = p.rot_b1 + ch*256;
      #pragma unroll
      for (int e = 0; e < 2; ++e){
        f32x4* rc = e ? r1 : r0;
        int h1o = ATTe + e*14784;
        #pragma unroll
        for (int m = 0; m < 4; ++m){
          #pragma unroll
          for (int j = 0; j < 4; ++j){
            int row = m*16 + hi*4 + j;
            if (row < 56) su[h1o + row*264 + col] = f2b(gelu_f(rc[m][j] + rb[col]));
          }
        }
      }
      __syncthreads();
      if (tt < 330){
        int h1o = ATTe + eh*14784;
        for (int d = 0; d < 256; ++d)
          pacc = fmaf(b2f(su[h1o + mp*264 + d]), p.rot_W2[(size_t)(ch*256 + d)*6 + op], pacc);
      }
      __syncthreads();
    }
    if (tt < 330) p.out[(size_t)(b2+eh)*330 + tt] = pacc + p.rot_b2[op];
  }

  // ---- transl head ----
  {
    #pragma unroll
    for (int hf = 0; hf < 2; ++hf){
      int c = tt + hf*512;
      float a = p.tr_b1[c];
      for (int k = 0; k < 256; ++k) a = fmaf(sf[X55f + eh*256 + k], p.tr_W1[(size_t)k*1024 + c], a);
      sf[TRFf + eh*1024 + c] = gelu_f(a);
    }
    __syncthreads();
    float part = 0.f;
    #pragma unroll
    for (int hf = 0; hf < 2; ++hf){
      int c = tt + hf*512;
      part = fmaf(sf[TRFf + eh*1024 + c], p.tr_W2[c], part);
    }
    part = wred_sum(part);
    if (lane == 0) sf[WSUMf + wv] = part;
    __syncthreads();
    if (t == 0){
      float s = p.tr_b2[0];
      #pragma unroll
      for (int w = 0; w < 8; ++w) s += sf[WSUMf + w];
      p.out[OUT_TR + b2] = s;
    }
    if (t == 512){
      float s = p.tr_b2[0];
      #pragma unroll
      for (int w = 8; w < 16; ++w) s += sf[WSUMf + w];
      p.out[OUT_TR + b2 + 1] = s;
    }
  }
}

extern "C" void kernel_launch(void* const* d_in, const int* in_sizes, int n_in,
                              void* d_out, int out_size, void* d_ws, size_t ws_size,
                              hipStream_t stream){
  (void)in_sizes; (void)n_in; (void)out_size; (void)ws_size;
  auto F = [&](int i) -> const float* { return (const float*)d_in[i]; };

  PP pp;
  pp.sa_Wqkv = F(20); pp.sa_Wo = F(22); pp.ff_W1 = F(30); pp.ff_W2 = F(32);
  pp.rot_W1 = F(40); pp.pose_W2 = F(5);
  pp.wb = (unsigned short*)d_ws;
  hipLaunchKernelGGL(prep_kernel, dim3((WTOT + 255u)/256u), dim3(256), 0, stream, pp);

  KP p;
  p.bp = F(0); p.wrist = F(1); p.betas = F(2);
  p.pose_W1 = F(3); p.pose_b1 = F(4); p.pose_b2 = F(6);
  p.joints = F(7); p.mask_emb = F(8); p.transl_emb = F(9);
  p.in_g = F(10); p.in_b = F(11);
  p.gender_tab = F(12);
  p.cond_W1 = F(13); p.cond_b1 = F(14); p.cond_W2 = F(15); p.cond_b2 = F(16);
  p.cond_g = F(17); p.cond_b = F(18);
  p.rel_map = F(19);
  p.sa_bqkv = F(21); p.sa_bo = F(23);
  p.ca_Wkv = F(26); p.ca_bkv = F(27); p.ca_Wo = F(28); p.ca_bo = F(29);
  p.ff_b1 = F(31); p.ff_b2 = F(33);
  p.ln1_g = F(34); p.ln1_b = F(35); p.ln2_g = F(36); p.ln2_b = F(37);
  p.ln3_g = F(38); p.ln3_b = F(39);
  p.rot_b1 = F(41); p.rot_W2 = F(42); p.rot_b2 = F(43);
  p.tr_W1 = F(44); p.tr_b1 = F(45); p.tr_W2 = F(46); p.tr_b2 = F(47);
  p.gender = (const int*)d_in[48]; p.mask_ids = (const int*)d_in[49];
  p.wb = (const unsigned short*)d_ws;
  p.out = (float*)d_out;

  hipLaunchKernelGGL(actor_kernel, dim3(NB), dim3(Tc), 0, stream, p);
}

// Round 10
// 6202.172 us; speedup vs baseline: 3.7714x; 1.0250x over previous
//
#include <hip/hip_runtime.h>
#include <hip/hip_bf16.h>

#define DEV static __device__ __forceinline__

typedef __attribute__((ext_vector_type(8))) short short8;
typedef __attribute__((ext_vector_type(4))) float f32x4;
#define MFMA16(a,b,c) __builtin_amdgcn_mfma_f32_16x16x32_bf16(a,b,c,0,0,0)

constexpr int Tc = 1024;
constexpr int NB = 1024;              // blocks; 2 batch elems each
constexpr int OUT_TR = 675840;
constexpr int OUT_AW = 677888;

// ---- d_ws bf16 frag-linear (u16 offsets) ----
constexpr unsigned WQKV = 0;          // l4 x hp4 x ks8 x ct12 x 512 (q-scale folded)
constexpr unsigned WO   = 786432;     // l4 x h8 x ct16 x 512   (K=32 per head)
constexpr unsigned WF1  = 1048576;    // l4 x ch4 x ks8 x ct16 x 512
constexpr unsigned WF2  = 2097152;    // l4 x ch4(k) x ks8 x ct16 x 512
constexpr unsigned WROT = 3145728;    // ch4 x ks8 x ct16 x 512
constexpr unsigned WP2  = 3407872;    // ks8 x ct16 x 512
constexpr unsigned WTOT = 3473408;

// ---- LDS (bytes) ----
constexpr int XB0 = 0;                // u16 [56][264]
constexpr int XB1 = 29568;
constexpr int ATT = 59136;            // 79360-byte arena
constexpr int STATS = 138496;         // f32 [2][128] (mean|rstd)
constexpr int CONDV = 140544;         // f32 [2][256]
constexpr int X55  = 142592;          // f32 [2][256] (also condin)
constexpr int SMEM_TOT = 144640;

// u16 offsets in arena
constexpr int ATTe = ATT/2;
constexpr int QPo  = ATTe;            // (e*2+hh)*2240 + row*40 + d
constexpr int KPo  = ATTe + 8960;
constexpr int VTo  = ATTe + 17920;    // (e*2+hh)*2304 + d*72 + row
constexpr int SCBo = ATTe + 27136;    // e*4032 + row*72 + key
constexpr int SCST = 4032;
constexpr int OHo  = ATTe + 35200;    // e*2240 + row*40 + d
// f32 indices (into (float*)smem)
constexpr int PARTS_S  = 14784;       // [2][16][64]
constexpr int PARTS_S2 = 16832;
constexpr int PARTSGf  = 14784;       // GEMV partials [2][2][256]
constexpr int VCSBf    = 15808;
constexpr int OCVf     = 16320;
constexpr int TMPFf    = 16832;       // cond hidden [2][512]
constexpr int BPFf     = 29568;       // body_pose stage [2][330]
constexpr int TRFf     = 14784;       // transl hidden [2][1024]
constexpr int STATSf   = 34624;
constexpr int WSUMf    = 34624;
constexpr int CONDVf   = 35136;
constexpr int X55f     = 35648;

struct PP {
  const float *sa_Wqkv,*sa_Wo,*ff_W1,*ff_W2,*rot_W1,*pose_W2;
  unsigned short* wb;
};
struct KP {
  const float *bp,*wrist,*betas;
  const float *pose_W1,*pose_b1,*pose_b2;
  const float *joints,*mask_emb,*transl_emb,*in_g,*in_b;
  const float *gender_tab,*cond_W1,*cond_b1,*cond_W2,*cond_b2,*cond_g,*cond_b;
  const float *rel_map;
  const float *sa_bqkv,*sa_bo;
  const float *ca_Wkv,*ca_bkv,*ca_Wo,*ca_bo;
  const float *ff_b1,*ff_b2;
  const float *ln1_g,*ln1_b,*ln2_g,*ln2_b,*ln3_g,*ln3_b;
  const float *rot_b1,*rot_W2,*rot_b2;
  const float *tr_W1,*tr_b1,*tr_W2,*tr_b2;
  const int *gender,*mask_ids;
  const unsigned short* wb;
  float* out;
};

DEV unsigned short f2b(float x){
  union { __hip_bfloat16 h; unsigned short u; } c; c.h = __float2bfloat16(x); return c.u;
}
DEV float b2f(unsigned short u){
  union { __hip_bfloat16 h; unsigned short u; } c; c.u = u; return __bfloat162float(c.h);
}
DEV float gelu_f(float x){
  float z = 0.7978845608028654f * (x + 0.044715f * x * x * x);
  return x / (1.0f + __expf(-2.0f * z));
}
DEV float wred_sum(float v){
  #pragma unroll
  for (int m = 32; m; m >>= 1) v += __shfl_xor(v, m, 64);
  return v;
}
DEV float wred_max(float v){
  #pragma unroll
  for (int m = 32; m; m >>= 1) v = fmaxf(v, __shfl_xor(v, m, 64));
  return v;
}

// ================= prep =================
__global__ __launch_bounds__(256)
void prep_kernel(PP a){
  unsigned i = blockIdx.x*256u + threadIdx.x;
  if (i >= WTOT) return;
  float v;
  if (i < WO){                                   // WQKV
    unsigned l=i/196608u, r=i%196608u, hp=r/49152u, r2=r%49152u;
    unsigned ks=r2/6144u, r3=r2%6144u, ct=r3/512u, r4=r3&511u;
    unsigned lane=r4>>3, e=r4&7u;
    unsigned c192=ct*16u+(lane&15u), k=ks*32u+((lane>>4)<<3)+e;
    unsigned part=c192>>6, hh=(c192>>5)&1u, d=c192&31u;
    v = a.sa_Wqkv[l*196608u + k*768u + part*256u + (hp*2u+hh)*32u + d];
    if (part==0u) v *= 0.17677669529663687f;
  } else if (i < WF1){                           // WO per-head K=32
    unsigned j=i-WO, l=j/65536u, r=j%65536u, h=r/8192u, r2=r%8192u;
    unsigned ct=r2/512u, r4=r2&511u, lane=r4>>3, e=r4&7u;
    unsigned col=ct*16u+(lane&15u), k=((lane>>4)<<3)+e;
    v = a.sa_Wo[l*65536u + (h*32u+k)*256u + col];
  } else if (i < WF2){                           // WF1
    unsigned j=i-WF1, l=j/262144u, r=j%262144u, ch=r/65536u, r2=r%65536u;
    unsigned ks=r2/8192u, r3=r2%8192u, ct=r3/512u, r4=r3&511u, lane=r4>>3, e=r4&7u;
    unsigned col=ct*16u+(lane&15u), k=ks*32u+((lane>>4)<<3)+e;
    v = a.ff_W1[l*262144u + k*1024u + ch*256u + col];
  } else if (i < WROT){                          // WF2
    unsigned j=i-WF2, l=j/262144u, r=j%262144u, ch=r/65536u, r2=r%65536u;
    unsigned ks=r2/8192u, r3=r2%8192u, ct=r3/512u, r4=r3&511u, lane=r4>>3, e=r4&7u;
    unsigned col=ct*16u+(lane&15u), k=ks*32u+((lane>>4)<<3)+e;
    v = a.ff_W2[l*262144u + (ch*256u+k)*256u + col];
  } else if (i < WP2){                           // WROT
    unsigned j=i-WROT, ch=j/65536u, r2=j%65536u;
    unsigned ks=r2/8192u, r3=r2%8192u, ct=r3/512u, r4=r3&511u, lane=r4>>3, e=r4&7u;
    unsigned col=ct*16u+(lane&15u), k=ks*32u+((lane>>4)<<3)+e;
    v = a.rot_W1[k*1024u + ch*256u + col];
  } else {                                       // WP2
    unsigned j=i-WP2, ks=j/8192u, r3=j%8192u;
    unsigned ct=r3/512u, r4=r3&511u, lane=r4>>3, e=r4&7u;
    unsigned col=ct*16u+(lane&15u), k=ks*32u+((lane>>4)<<3)+e;
    v = a.pose_W2[k*256u + col];
  }
  a.wb[i] = f2b(v);
}

// ================= helpers =================
// E=2 GEMM: B frag-linear from global, depth-2 pipelined (8 VGPRs of B, not 32).
// A pad-rows 56..63 read in-bounds LDS garbage -> only discarded C rows (stores guard row<56).
DEV void gemm2(const unsigned short* su, int a0o, int a1o, int astr,
               const unsigned short* Bg, int ct, int nct,
               f32x4* C0, f32x4* C1, int lane){
  const unsigned short* A0 = su + a0o + (lane & 15)*astr + ((lane >> 4) << 3);
  const unsigned short* A1 = su + a1o + (lane & 15)*astr + ((lane >> 4) << 3);
  short8 bcur = *(const short8*)(Bg + (size_t)ct*512 + lane*8);
  #pragma unroll
  for (int ks = 0; ks < 8; ++ks){
    short8 bnext = bcur;
    if (ks < 7) bnext = *(const short8*)(Bg + (size_t)((ks+1)*nct + ct)*512 + lane*8);
    #pragma unroll
    for (int m = 0; m < 4; ++m){
      short8 a0 = *(const short8*)(A0 + m*16*astr + ks*32);
      C0[m] = MFMA16(a0, bcur, C0[m]);
      short8 a1 = *(const short8*)(A1 + m*16*astr + ks*32);
      C1[m] = MFMA16(a1, bcur, C1[m]);
    }
    bcur = bnext;
  }
}

__global__ __launch_bounds__(Tc, 4) __attribute__((amdgpu_waves_per_eu(4, 4)))
void actor_kernel(KP p){
  __shared__ __align__(16) char smem[SMEM_TOT];
  float* sf = (float*)smem;
  unsigned short* su = (unsigned short*)smem;

  const int t = threadIdx.x;
  const int lane = t & 63, wv = t >> 6;
  const int hi = lane >> 4;
  const int col = wv*16 + (lane & 15);
  const int b2 = blockIdx.x * 2;
  const int eh = t >> 9, tt = t & 511;   // elem-half split
  const f32x4 fz = {0.f,0.f,0.f,0.f};

  f32x4 xsr[2][4];                       // x fp32 resident in regs (16-col slice)
  float awr[7] = {0,0,0,0,0,0,0};

  // ---- LN over reg-x: 2(+1 if wxb) barriers ----
  auto ln_regs = [&](const float* g, const float* bta, bool wxb){
    #pragma unroll
    for (int e = 0; e < 2; ++e){
      #pragma unroll
      for (int m = 0; m < 4; ++m){
        #pragma unroll
        for (int j = 0; j < 4; ++j){
          float s = xsr[e][m][j], s2 = s*s;
          #pragma unroll
          for (int mk = 1; mk < 16; mk <<= 1){
            s += __shfl_xor(s, mk, 64); s2 += __shfl_xor(s2, mk, 64);
          }
          if ((lane & 15) == 0){
            int row = m*16 + hi*4 + j;
            sf[PARTS_S  + (e*16 + wv)*64 + row] = s;
            sf[PARTS_S2 + (e*16 + wv)*64 + row] = s2;
          }
        }
      }
    }
    __syncthreads();
    if (t < 128){
      int e = t >> 6, row = t & 63;
      float s = 0.f, s2 = 0.f;
      #pragma unroll
      for (int w = 0; w < 16; ++w){
        s  += sf[PARTS_S  + (e*16 + w)*64 + row];
        s2 += sf[PARTS_S2 + (e*16 + w)*64 + row];
      }
      float mean = s * (1.f/256.f);
      float var  = s2 * (1.f/256.f) - mean*mean;
      sf[STATSf + e*128 + row]      = mean;
      sf[STATSf + e*128 + 64 + row] = rsqrtf(var + 1e-5f);
    }
    __syncthreads();
    float gg = g[col], bb = bta[col];
    #pragma unroll
    for (int e = 0; e < 2; ++e){
      int xbo = (e ? XB1 : XB0) / 2;
      #pragma unroll
      for (int m = 0; m < 4; ++m){
        #pragma unroll
        for (int j = 0; j < 4; ++j){
          int row = m*16 + hi*4 + j;
          float mean = sf[STATSf + e*128 + row];
          float rstd = sf[STATSf + e*128 + 64 + row];
          float o = (xsr[e][m][j] - mean) * rstd * gg + bb;
          xsr[e][m][j] = o;
          if (wxb && row < 56) su[xbo + row*264 + col] = f2b(o);
        }
      }
    }
    if (wxb) __syncthreads();
  };

  // ================= prologue =================
  if (tt < 29){
    float v;
    if (tt < 10) v = p.wrist[(b2+eh)*10 + tt];
    else if (tt < 13) v = p.betas[(b2+eh)*3 + (tt-10)];
    else { int g = p.gender[b2+eh]; v = p.gender_tab[g*16 + (tt-13)]; }
    sf[X55f + eh*256 + tt] = v;          // condin
  }
  if (tt < 330) sf[BPFf + eh*330 + tt] = p.bp[(size_t)(b2+eh)*330 + tt];
  __syncthreads();
  // cond W1
  {
    float a = p.cond_b1[tt];
    #pragma unroll 1
    for (int k = 0; k < 29; ++k) a = fmaf(sf[X55f + eh*256 + k], p.cond_W1[k*512 + tt], a);
    sf[TMPFf + eh*512 + tt] = gelu_f(a);
  }
  __syncthreads();
  // cond W2 (2-way k-split per elem)
  {
    int c = tt & 255, pg = tt >> 8;
    float a = 0.f;
    for (int k = pg*256; k < pg*256 + 256; ++k)
      a = fmaf(sf[TMPFf + eh*512 + k], p.cond_W2[(size_t)k*256 + c], a);
    sf[PARTSGf + (eh*2 + pg)*256 + c] = a;
  }
  __syncthreads();
  if (t < 512){
    int e = t >> 8, c = t & 255;
    sf[CONDVf + e*256 + c] = p.cond_b2[c] + sf[PARTSGf + (e*2)*256 + c] + sf[PARTSGf + (e*2+1)*256 + c];
  }
  __syncthreads();
  if (wv == 0 || wv == 8){
    int e = wv >> 3;
    float v[4], s = 0.f, s2 = 0.f;
    #pragma unroll
    for (int u = 0; u < 4; ++u){ v[u] = sf[CONDVf + e*256 + lane + 64*u]; s += v[u]; s2 = fmaf(v[u], v[u], s2); }
    s = wred_sum(s); s2 = wred_sum(s2);
    float mean = s * (1.f/256.f);
    float var  = s2 * (1.f/256.f) - mean*mean;
    float rs = rsqrtf(var + 1e-5f);
    #pragma unroll
    for (int u = 0; u < 4; ++u){
      int n = lane + 64*u;
      sf[CONDVf + e*256 + n] = (v[u]-mean)*rs*p.cond_g[n] + p.cond_b[n];
    }
  }
  __syncthreads();
  // embed W1 -> h1 (arena)
  {
    int n = tt & 255, mb = tt >> 8;
    int h1o = ATTe + eh*14784;
    for (int m = mb; m < 55; m += 2){
      float a = p.pose_b1[n];
      #pragma unroll
      for (int k = 0; k < 6; ++k) a = fmaf(sf[BPFf + eh*330 + m*6 + k], p.pose_W1[k*256 + n], a);
      su[h1o + m*264 + n] = f2b(gelu_f(a));
    }
    if (t < 512) su[ATTe + (t>>8)*14784 + 55*264 + (t&255)] = 0;
  }
  __syncthreads();
  // embed GEMM + fixups -> xsr
  {
    f32x4 a0[4] = {fz,fz,fz,fz}, a1[4] = {fz,fz,fz,fz};
    gemm2(su, ATTe, ATTe + 14784, 264, p.wb + WP2, wv, 16, a0, a1, lane);
    #pragma unroll
    for (int e = 0; e < 2; ++e){
      f32x4* ac = e ? a1 : a0;
      #pragma unroll
      for (int m = 0; m < 4; ++m){
        #pragma unroll
        for (int j = 0; j < 4; ++j){
          int row = m*16 + hi*4 + j;
          float v = 0.f;
          if (row < 56){
            v = (row < 55) ? (ac[m][j] + p.pose_b2[col]) : p.transl_emb[col];
            v = p.mask_ids[(b2+e)*56 + row] ? v : p.mask_emb[col];
            v += p.joints[row*256 + col];
          }
          xsr[e][m][j] = v;
        }
      }
    }
  }
  __syncthreads();
  ln_regs(p.in_g, p.in_b, true);

  // ================= layers =================
  for (int l = 0; l < 4; ++l){
    const float* bqkv = p.sa_bqkv + l*768;

    for (int hp = 0; hp < 4; ++hp){
      // zero vT key-pads for both elems/heads
      {
        int e = t >> 9, hh2 = (t >> 8) & 1, d = (t >> 3) & 31, pd = t & 7;
        su[VTo + (e*2 + hh2)*2304 + d*72 + 56 + pd] = 0;
      }
      // QKV head-pair GEMM (N=192): waves 0..11
      if (wv < 12){
        f32x4 q0[4] = {fz,fz,fz,fz}, q1[4] = {fz,fz,fz,fz};
        gemm2(su, XB0/2, XB1/2, 264, p.wb + WQKV + (size_t)(l*4 + hp)*49152, wv, 12, q0, q1, lane);
        int c192 = wv*16 + (lane & 15);
        int part = c192 >> 6, hh2 = (c192 >> 5) & 1, d = c192 & 31;
        float bias = bqkv[part*256 + (hp*2 + hh2)*32 + d];
        if (part == 0) bias *= 0.17677669529663687f;
        #pragma unroll
        for (int e = 0; e < 2; ++e){
          f32x4* ac = e ? q1 : q0;
          #pragma unroll
          for (int m = 0; m < 4; ++m){
            #pragma unroll
            for (int j = 0; j < 4; ++j){
              int row = m*16 + hi*4 + j;
              if (row < 56){
                float v = ac[m][j] + bias;
                if (part == 0)      su[QPo + (e*2+hh2)*2240 + row*40 + d] = f2b(v);
                else if (part == 1) su[KPo + (e*2+hh2)*2240 + row*40 + d] = f2b(v);
                else                su[VTo + (e*2+hh2)*2304 + d*72 + row] = f2b(v);
              }
            }
          }
        }
      }
      __syncthreads();

      for (int hh = 0; hh < 2; ++hh){
        int e = wv >> 3, wq = wv & 7;
        // scores: 2 tiles per wave (m = wq>>1, n = (wq&1)*2 + i)
        {
          int m = wq >> 1;
          short8 a = *(const short8*)(su + QPo + (e*2+hh)*2240 + (m*16 + (lane&15))*40 + (hi<<3));
          #pragma unroll
          for (int i = 0; i < 2; ++i){
            int n = (wq & 1)*2 + i;
            short8 bf_ = *(const short8*)(su + KPo + (e*2+hh)*2240 + (n*16 + (lane&15))*40 + (hi<<3));
            f32x4 d = MFMA16(a, bf_, fz);
            #pragma unroll
            for (int j = 0; j < 4; ++j){
              int row = m*16 + hi*4 + j, key = n*16 + (lane & 15);
              if (row < 56 && key < 56)
                su[SCBo + e*SCST + row*72 + key] = f2b(d[j] + p.rel_map[row*56 + key]);
            }
          }
        }
        __syncthreads();
        // softmax: 7 rows per wave
        #pragma unroll
        for (int q = 0; q < 7; ++q){
          int r = wq*7 + q;
          float v = (lane < 56) ? b2f(su[SCBo + e*SCST + r*72 + lane]) : -3.0e38f;
          float mx = wred_max(v);
          float ex = (lane < 56) ? __expf(v - mx) : 0.f;
          float s = wred_sum(ex);
          float a = ex / s;
          su[SCBo + e*SCST + r*72 + lane] = (lane < 56) ? f2b(a) : (unsigned short)0;
          if (l == 3) awr[q] += a * 0.125f;
        }
        __syncthreads();
        // PV: 1 tile per wave (m = wq>>1, dt = wq&1)
        {
          int m = wq >> 1, dt = wq & 1;
          f32x4 o = fz;
          #pragma unroll
          for (int ks = 0; ks < 2; ++ks){
            short8 a  = *(const short8*)(su + SCBo + e*SCST + (m*16 + (lane&15))*72 + ks*32 + (hi<<3));
            short8 bf_= *(const short8*)(su + VTo + (e*2+hh)*2304 + (dt*16 + (lane&15))*72 + ks*32 + (hi<<3));
            o = MFMA16(a, bf_, o);
          }
          #pragma unroll
          for (int j = 0; j < 4; ++j){
            int row = m*16 + hi*4 + j;
            if (row < 56) su[OHo + e*2240 + row*40 + dt*16 + (lane & 15)] = f2b(o[j]);
          }
        }
        __syncthreads();
        // AO (K=32) accumulate into xsr
        {
          short8 bo = *(const short8*)(p.wb + WO + (size_t)(((l*8 + hp*2 + hh)*16) + wv)*512 + lane*8);
          #pragma unroll
          for (int e2 = 0; e2 < 2; ++e2){
            #pragma unroll
            for (int m = 0; m < 4; ++m){
              short8 a = *(const short8*)(su + OHo + e2*2240 + (m*16 + (lane&15))*40 + (hi<<3));
              xsr[e2][m] = MFMA16(a, bo, xsr[e2][m]);
            }
          }
        }
        __syncthreads();
      }
    } // head pairs

    // AO bias + LN1
    {
      float bo = p.sa_bo[l*256 + col];
      #pragma unroll
      for (int e = 0; e < 2; ++e)
        #pragma unroll
        for (int m = 0; m < 4; ++m)
          #pragma unroll
          for (int j = 0; j < 4; ++j) xsr[e][m][j] += bo;
    }
    ln_regs(p.ln1_g + l*256, p.ln1_b + l*256, false);

    // collapsed cross-attn (2 GEMVs, 2-way k-split per elem)
    __syncthreads();  // protect PARTSG (overlaps stats users done above)
    {
      int c = tt & 255, pg = tt >> 8;
      float a = 0.f;
      const float* W = p.ca_Wkv + (size_t)l*131072 + 256 + c;
      for (int k = pg*128; k < pg*128 + 128; ++k) a = fmaf(sf[CONDVf + eh*256 + k], W[(size_t)k*512], a);
      sf[PARTSGf + (eh*2 + pg)*256 + c] = a;
    }
    __syncthreads();
    if (t < 512){
      int e = t >> 8, c = t & 255;
      sf[VCSBf + e*256 + c] = p.ca_bkv[l*512 + 256 + c] + sf[PARTSGf + e*2*256 + c] + sf[PARTSGf + (e*2+1)*256 + c];
    }
    __syncthreads();
    {
      int c = tt & 255, pg = tt >> 8;
      float a = 0.f;
      const float* W = p.ca_Wo + (size_t)l*65536 + c;
      for (int k = pg*128; k < pg*128 + 128; ++k) a = fmaf(sf[VCSBf + eh*256 + k], W[(size_t)k*256], a);
      sf[PARTSGf + (eh*2 + pg)*256 + c] = a;
    }
    __syncthreads();
    if (t < 512){
      int e = t >> 8, c = t & 255;
      sf[OCVf + e*256 + c] = p.ca_bo[l*256 + c] + sf[PARTSGf + e*2*256 + c] + sf[PARTSGf + (e*2+1)*256 + c];
    }
    __syncthreads();
    {
      float o0 = sf[OCVf + col], o1 = sf[OCVf + 256 + col];
      #pragma unroll
      for (int m = 0; m < 4; ++m)
        #pragma unroll
        for (int j = 0; j < 4; ++j){ xsr[0][m][j] += o0; xsr[1][m][j] += o1; }
    }
    __syncthreads();  // OCV reads done before LN partials overwrite region
    ln_regs(p.ln2_g + l*256, p.ln2_b + l*256, true);

    // FF
    for (int ch = 0; ch < 4; ++ch){
      f32x4 f0[4] = {fz,fz,fz,fz}, f1[4] = {fz,fz,fz,fz};
      gemm2(su, XB0/2, XB1/2, 264, p.wb + WF1 + (size_t)(l*4 + ch)*65536, wv, 16, f0, f1, lane);
      const float* b1 = p.ff_b1 + l*1024 + ch*256;
      #pragma unroll
      for (int e = 0; e < 2; ++e){
        f32x4* fc = e ? f1 : f0;
        int h1o = ATTe + e*14784;
        #pragma unroll
        for (int m = 0; m < 4; ++m){
          #pragma unroll
          for (int j = 0; j < 4; ++j){
            int row = m*16 + hi*4 + j;
            if (row < 56) su[h1o + row*264 + col] = f2b(gelu_f(fc[m][j] + b1[col]));
          }
        }
      }
      __syncthreads();
      gemm2(su, ATTe, ATTe + 14784, 264, p.wb + WF2 + (size_t)(l*4 + ch)*65536, wv, 16, xsr[0], xsr[1], lane);
      __syncthreads();
    }
    {
      float bo = p.ff_b2[l*256 + col];
      #pragma unroll
      for (int e = 0; e < 2; ++e)
        #pragma unroll
        for (int m = 0; m < 4; ++m)
          #pragma unroll
          for (int j = 0; j < 4; ++j) xsr[e][m][j] += bo;
    }
    ln_regs(p.ln3_g + l*256, p.ln3_b + l*256, true);
  } // layers

  // ---- attn_w out ----
  {
    int e = wv >> 3, wq = wv & 7;
    if (lane < 56){
      #pragma unroll
      for (int q = 0; q < 7; ++q)
        p.out[OUT_AW + (size_t)(b2+e)*3136 + (wq*7 + q)*56 + lane] = awr[q];
    }
  }
  // ---- x row 55 -> LDS for transl ----
  if (hi == 1){
    sf[X55f + 0*256 + col] = xsr[0][3][3];
    sf[X55f + 1*256 + col] = xsr[1][3][3];
  }

  // ---- pose head ----
  {
    float pacc = 0.f;
    int mp = tt / 6, op = tt - mp*6;
    for (int ch = 0; ch < 4; ++ch){
      f32x4 r0[4] = {fz,fz,fz,fz}, r1[4] = {fz,fz,fz,fz};
      gemm2(su, XB0/2, XB1/2, 264, p.wb + WROT + (size_t)ch*65536, wv, 16, r0, r1, lane);
      const float* rb = p.rot_b1 + ch*256;
      #pragma unroll
      for (int e = 0; e < 2; ++e){
        f32x4* rc = e ? r1 : r0;
        int h1o = ATTe + e*14784;
        #pragma unroll
        for (int m = 0; m < 4; ++m){
          #pragma unroll
          for (int j = 0; j < 4; ++j){
            int row = m*16 + hi*4 + j;
            if (row < 56) su[h1o + row*264 + col] = f2b(gelu_f(rc[m][j] + rb[col]));
          }
        }
      }
      __syncthreads();
      if (tt < 330){
        int h1o = ATTe + eh*14784;
        for (int d = 0; d < 256; ++d)
          pacc = fmaf(b2f(su[h1o + mp*264 + d]), p.rot_W2[(size_t)(ch*256 + d)*6 + op], pacc);
      }
      __syncthreads();
    }
    if (tt < 330) p.out[(size_t)(b2+eh)*330 + tt] = pacc + p.rot_b2[op];
  }

  // ---- transl head ----
  {
    #pragma unroll
    for (int hf = 0; hf < 2; ++hf){
      int c = tt + hf*512;
      float a = p.tr_b1[c];
      for (int k = 0; k < 256; ++k) a = fmaf(sf[X55f + eh*256 + k], p.tr_W1[(size_t)k*1024 + c], a);
      sf[TRFf + eh*1024 + c] = gelu_f(a);
    }
    __syncthreads();
    float part = 0.f;
    #pragma unroll
    for (int hf = 0; hf < 2; ++hf){
      int c = tt + hf*512;
      part = fmaf(sf[TRFf + eh*1024 + c], p.tr_W2[c], part);
    }
    part = wred_sum(part);
    if (lane == 0) sf[WSUMf + wv] = part;
    __syncthreads();
    if (t == 0){
      float s = p.tr_b2[0];
      #pragma unroll
      for (int w = 0; w < 8; ++w) s += sf[WSUMf + w];
      p.out[OUT_TR + b2] = s;
    }
    if (t == 512){
      float s = p.tr_b2[0];
      #pragma unroll
      for (int w = 8; w < 16; ++w) s += sf[WSUMf + w];
      p.out[OUT_TR + b2 + 1] = s;
    }
  }
}

extern "C" void kernel_launch(void* const* d_in, const int* in_sizes, int n_in,
                              void* d_out, int out_size, void* d_ws, size_t ws_size,
                              hipStream_t stream){
  (void)in_sizes; (void)n_in; (void)out_size; (void)ws_size;
  auto F = [&](int i) -> const float* { return (const float*)d_in[i]; };

  PP pp;
  pp.sa_Wqkv = F(20); pp.sa_Wo = F(22); pp.ff_W1 = F(30); pp.ff_W2 = F(32);
  pp.rot_W1 = F(40); pp.pose_W2 = F(5);
  pp.wb = (unsigned short*)d_ws;
  hipLaunchKernelGGL(prep_kernel, dim3((WTOT + 255u)/256u), dim3(256), 0, stream, pp);

  KP p;
  p.bp = F(0); p.wrist = F(1); p.betas = F(2);
  p.pose_W1 = F(3); p.pose_b1 = F(4); p.pose_b2 = F(6);
  p.joints = F(7); p.mask_emb = F(8); p.transl_emb = F(9);
  p.in_g = F(10); p.in_b = F(11);
  p.gender_tab = F(12);
  p.cond_W1 = F(13); p.cond_b1 = F(14); p.cond_W2 = F(15); p.cond_b2 = F(16);
  p.cond_g = F(17); p.cond_b = F(18);
  p.rel_map = F(19);
  p.sa_bqkv = F(21); p.sa_bo = F(23);
  p.ca_Wkv = F(26); p.ca_bkv = F(27); p.ca_Wo = F(28); p.ca_bo = F(29);
  p.ff_b1 = F(31); p.ff_b2 = F(33);
  p.ln1_g = F(34); p.ln1_b = F(35); p.ln2_g = F(36); p.ln2_b = F(37);
  p.ln3_g = F(38); p.ln3_b = F(39);
  p.rot_b1 = F(41); p.rot_W2 = F(42); p.rot_b2 = F(43);
  p.tr_W1 = F(44); p.tr_b1 = F(45); p.tr_W2 = F(46); p.tr_b2 = F(47);
  p.gender = (const int*)d_in[48]; p.mask_ids = (const int*)d_in[49];
  p.wb = (const unsigned short*)d_ws;
  p.out = (float*)d_out;

  hipLaunchKernelGGL(actor_kernel, dim3(NB), dim3(Tc), 0, stream, p);
}